// Round 1
// baseline (796.914 us; speedup 1.0000x reference)
//
#include <hip/hip_runtime.h>

#define TAU_INV 5.0f

using ushort = unsigned short;
typedef __attribute__((ext_vector_type(8))) short s16x8;
typedef __attribute__((ext_vector_type(4))) float f32x4;

static __device__ __forceinline__ ushort f2bf(float x) {
  unsigned u = __float_as_uint(x);
  return (ushort)((u + 0x7fffu + ((u >> 16) & 1u)) >> 16);
}

// ---------------- elementwise f32 -> bf16 ----------------
__global__ void k_cvt_bf16(const float* __restrict__ in, ushort* __restrict__ o, int n4) {
  int i = blockIdx.x * blockDim.x + threadIdx.x;
  if (i >= n4) return;
  float4 v = ((const float4*)in)[i];
  ushort4 r;
  r.x = f2bf(v.x); r.y = f2bf(v.y); r.z = f2bf(v.z); r.w = f2bf(v.w);
  ((ushort4*)o)[i] = r;
}

// ---------------- transpose + convert: W[K,N] f32 -> Wt[N,K] bf16 ----------------
__global__ void k_transpose_cvt(const float* __restrict__ W, ushort* __restrict__ Wt, int K, int N) {
  __shared__ float tile[32][33];
  int n0 = blockIdx.x * 32, k0 = blockIdx.y * 32;
  int tx = threadIdx.x & 31, ty = threadIdx.x >> 5;
#pragma unroll
  for (int i = 0; i < 32; i += 8)
    tile[ty + i][tx] = W[(size_t)(k0 + ty + i) * N + n0 + tx];
  __syncthreads();
#pragma unroll
  for (int i = 0; i < 32; i += 8)
    Wt[(size_t)(n0 + ty + i) * K + k0 + tx] = f2bf(tile[tx][ty + i]);
}

// ---------------- MFMA GEMM: C = A[M,K] @ B[N,K]^T, bf16 in / f32 acc ----------------
// EPI 0: +bias, relu, store bf16 [Mvalid x ldOut]
// EPI 1: +bias, store f32
// EPI 2: per-row online (max, sumexp) of acc*scale -> partials [row][ntiles]
// EPI 3: per-row (max, argmax col) -> partials [(bz*Mvalid+row)][ntiles]
template <int EPI>
__global__ __launch_bounds__(256) void k_gemm_abt(
    const ushort* __restrict__ A, const ushort* __restrict__ B,
    const float* __restrict__ bias, void* __restrict__ o0, void* __restrict__ o1,
    int Mvalid, int Nvalid, int K, int ldOut, int ntiles, float scale,
    long sA, long sB) {
  __shared__ unsigned char smem[32768];
  unsigned char* As = smem;
  unsigned char* Bs = smem + 16384;
  const int tid = threadIdx.x;
  const int bx = blockIdx.x, by = blockIdx.y, bz = blockIdx.z;
  const ushort* Ab = A + (size_t)bz * sA;
  const ushort* Bb = B + (size_t)bz * sB;
  const int mBase = by * 128, nBase = bx * 128;
  const int lane = tid & 63;
  const int wid = tid >> 6;
  const int wm = wid >> 1, wn = wid & 1;
  const int lg = lane >> 4, li = lane & 15;
  f32x4 acc[4][4] = {};

  for (int k0 = 0; k0 < K; k0 += 64) {
    __syncthreads();
#pragma unroll
    for (int i = 0; i < 4; ++i) {
      int q = tid + i * 256;
      int row = q >> 3, kc = (q & 7) << 3;
      int sw = ((kc << 1) ^ ((row & 7) << 4));
      float4 va = {0.f, 0.f, 0.f, 0.f}, vb = {0.f, 0.f, 0.f, 0.f};
      if (mBase + row < Mvalid) va = *(const float4*)(const void*)(Ab + (size_t)(mBase + row) * K + k0 + kc);
      if (nBase + row < Nvalid) vb = *(const float4*)(const void*)(Bb + (size_t)(nBase + row) * K + k0 + kc);
      *(float4*)(void*)(As + row * 128 + sw) = va;
      *(float4*)(void*)(Bs + row * 128 + sw) = vb;
    }
    __syncthreads();
#pragma unroll
    for (int ks = 0; ks < 2; ++ks) {
      s16x8 af[4], bfr[4];
#pragma unroll
      for (int mi = 0; mi < 4; ++mi) {
        int r = wm * 64 + mi * 16 + li;
        af[mi] = *(const s16x8*)(const void*)(As + r * 128 + ((ks * 64 + lg * 16) ^ ((r & 7) << 4)));
      }
#pragma unroll
      for (int ni = 0; ni < 4; ++ni) {
        int c = wn * 64 + ni * 16 + li;
        bfr[ni] = *(const s16x8*)(const void*)(Bs + c * 128 + ((ks * 64 + lg * 16) ^ ((c & 7) << 4)));
      }
#pragma unroll
      for (int mi = 0; mi < 4; ++mi)
#pragma unroll
        for (int ni = 0; ni < 4; ++ni)
          acc[mi][ni] = __builtin_amdgcn_mfma_f32_16x16x32_bf16(af[mi], bfr[ni], acc[mi][ni], 0, 0, 0);
    }
  }

  if constexpr (EPI <= 1) {
#pragma unroll
    for (int mi = 0; mi < 4; ++mi)
#pragma unroll
      for (int ni = 0; ni < 4; ++ni) {
        int c = nBase + wn * 64 + ni * 16 + li;
#pragma unroll
        for (int rg = 0; rg < 4; ++rg) {
          int r = mBase + wm * 64 + mi * 16 + lg * 4 + rg;
          if (r < Mvalid && c < Nvalid) {
            float v = acc[mi][ni][rg] + bias[c];
            if constexpr (EPI == 0) {
              v = fmaxf(v, 0.f);
              ((ushort*)o0)[(size_t)r * ldOut + c] = f2bf(v);
            } else {
              ((float*)o0)[(size_t)r * ldOut + c] = v;
            }
          }
        }
      }
  } else if constexpr (EPI == 2) {
    __syncthreads();
    float* redm = (float*)(void*)smem;   // [128][2]
    float* reds = redm + 256;            // [128][2]
#pragma unroll
    for (int mi = 0; mi < 4; ++mi)
#pragma unroll
      for (int rg = 0; rg < 4; ++rg) {
        float v0 = acc[mi][0][rg] * scale;
        float v1 = acc[mi][1][rg] * scale;
        float v2 = acc[mi][2][rg] * scale;
        float v3 = acc[mi][3][rg] * scale;
        float m = fmaxf(fmaxf(v0, v1), fmaxf(v2, v3));
        float s = expf(v0 - m) + expf(v1 - m) + expf(v2 - m) + expf(v3 - m);
#pragma unroll
        for (int d = 1; d < 16; d <<= 1) {
          float om = __shfl_xor(m, d);
          float os = __shfl_xor(s, d);
          float nm = fmaxf(m, om);
          s = s * expf(m - nm) + os * expf(om - nm);
          m = nm;
        }
        int rl = wm * 64 + mi * 16 + lg * 4 + rg;
        if (li == 0) { redm[rl * 2 + wn] = m; reds[rl * 2 + wn] = s; }
      }
    __syncthreads();
    if (tid < 128) {
      float m0 = redm[tid * 2], m1 = redm[tid * 2 + 1];
      float s0 = reds[tid * 2], s1 = reds[tid * 2 + 1];
      float m = fmaxf(m0, m1);
      float s = s0 * expf(m0 - m) + s1 * expf(m1 - m);
      size_t idx = (size_t)(mBase + tid) * ntiles + bx;
      ((float*)o0)[idx] = m;
      ((float*)o1)[idx] = s;
    }
  } else {
    __syncthreads();
    float* redv = (float*)(void*)smem;          // [128][2]
    int* redi = (int*)(void*)(smem + 1024);     // [128][2]
#pragma unroll
    for (int mi = 0; mi < 4; ++mi)
#pragma unroll
      for (int rg = 0; rg < 4; ++rg) {
        float bv = -3.4e38f;
        int bi = 0x7fffffff;
#pragma unroll
        for (int ni = 0; ni < 4; ++ni) {
          int c = nBase + wn * 64 + ni * 16 + li;
          float v = (c < Nvalid) ? acc[mi][ni][rg] : -3.4e38f;
          if (v > bv || (v == bv && c < bi)) { bv = v; bi = c; }
        }
#pragma unroll
        for (int d = 1; d < 16; d <<= 1) {
          float ov = __shfl_xor(bv, d);
          int oi = __shfl_xor(bi, d);
          if (ov > bv || (ov == bv && oi < bi)) { bv = ov; bi = oi; }
        }
        int rl = wm * 64 + mi * 16 + lg * 4 + rg;
        if (li == 0) { redv[rl * 2 + wn] = bv; redi[rl * 2 + wn] = bi; }
      }
    __syncthreads();
    if (tid < 128) {
      int r = mBase + tid;
      if (r < Mvalid) {
        float v0 = redv[tid * 2], v1 = redv[tid * 2 + 1];
        int i0 = redi[tid * 2], i1 = redi[tid * 2 + 1];
        float v = v0; int bi2 = i0;
        if (v1 > v || (v1 == v && i1 < bi2)) { v = v1; bi2 = i1; }
        size_t idx = (size_t)(bz * Mvalid + r) * ntiles + bx;
        ((float*)o0)[idx] = v;
        ((int*)o1)[idx] = bi2;
      }
    }
  }
}

// ---------------- row l2-normalize (128 wide), write f32 + bf16 ----------------
__global__ void k_l2n_rows(const float* __restrict__ raw, float* __restrict__ of,
                           ushort* __restrict__ ob, int rows) {
  int row = blockIdx.x * 4 + (threadIdx.x >> 6);
  int lane = threadIdx.x & 63;
  if (row >= rows) return;
  const float* rp = raw + (size_t)row * 128;
  float v0 = rp[lane], v1 = rp[lane + 64];
  float ss = v0 * v0 + v1 * v1;
#pragma unroll
  for (int d = 1; d < 64; d <<= 1) ss += __shfl_xor(ss, d);
  float r = 1.0f / sqrtf(fmaxf(ss, 1e-12f));
  of[(size_t)row * 128 + lane] = v0 * r;
  of[(size_t)row * 128 + lane + 64] = v1 * r;
  ob[(size_t)row * 128 + lane] = f2bf(v0 * r);
  ob[(size_t)row * 128 + lane + 64] = f2bf(v1 * r);
}

// ---------------- argmax finalize over 7 col-tiles + gather matched row ----------------
__global__ void k_argmax_gather(const float* __restrict__ pval, const int* __restrict__ pidx,
                                const ushort* __restrict__ kd_bf, ushort* __restrict__ matched_bf,
                                int* __restrict__ idxf) {
  int n = blockIdx.x;
  int b = n / 784;
  float bv = pval[(size_t)n * 7];
  int bi = pidx[(size_t)n * 7];
#pragma unroll
  for (int t = 1; t < 7; ++t) {
    float v = pval[(size_t)n * 7 + t];
    int i2 = pidx[(size_t)n * 7 + t];
    if (v > bv) { bv = v; bi = i2; }
  }
  int lane = threadIdx.x;
  if (lane == 0) idxf[n] = bi;
  const ushort* src = kd_bf + (size_t)(b * 784 + bi) * 128;
  ushort* dst = matched_bf + (size_t)n * 128;
  dst[lane] = src[lane];
  dst[lane + 64] = src[lane + 64];
}

// ---------------- global head (fp32, tiny) ----------------
__global__ void k_gpool(const float* __restrict__ feat, float* __restrict__ g) {
  int b = blockIdx.y;
  int c = blockIdx.x * 256 + threadIdx.x;
  const float* fp = feat + (size_t)b * 784 * 1024 + c;
  float s = 0.f;
  for (int p = 0; p < 784; ++p) s += fp[(size_t)p * 1024];
  g[b * 1024 + c] = s * (1.0f / 784.0f);
}

__global__ void k_dense1(const float* __restrict__ g, const float* __restrict__ W,
                         const float* __restrict__ bias, float* __restrict__ h) {
  int b = blockIdx.y;
  int d = blockIdx.x * 256 + threadIdx.x;
  float a = 0.f;
  for (int c = 0; c < 1024; ++c) a += g[b * 1024 + c] * W[(size_t)c * 2048 + d];
  h[b * 2048 + d] = fmaxf(a + bias[d], 0.f);
}

__global__ void k_dense2(const float* __restrict__ h, const float* __restrict__ W,
                         const float* __restrict__ bias, float* __restrict__ o) {
  int b = blockIdx.x;
  int p = threadIdx.x;
  float a = 0.f;
  for (int c = 0; c < 2048; ++c) a += h[b * 2048 + c] * W[(size_t)c * 128 + p];
  o[b * 128 + p] = a + bias[p];
}

__global__ void k_norm_small(const float* __restrict__ qraw, const float* __restrict__ kraw,
                             float* __restrict__ qg, float* __restrict__ kg,
                             float* __restrict__ lpos) {
  int b = blockIdx.x;
  int lane = threadIdx.x;
  float q0 = qraw[b * 128 + lane], q1 = qraw[b * 128 + 64 + lane];
  float k0 = kraw[b * 128 + lane], k1 = kraw[b * 128 + 64 + lane];
  float sq = q0 * q0 + q1 * q1, sk = k0 * k0 + k1 * k1;
#pragma unroll
  for (int d = 1; d < 64; d <<= 1) { sq += __shfl_xor(sq, d); sk += __shfl_xor(sk, d); }
  float rq = 1.0f / sqrtf(fmaxf(sq, 1e-12f));
  float rk = 1.0f / sqrtf(fmaxf(sk, 1e-12f));
  q0 *= rq; q1 *= rq; k0 *= rk; k1 *= rk;
  qg[b * 128 + lane] = q0; qg[b * 128 + 64 + lane] = q1;
  kg[b * 128 + lane] = k0; kg[b * 128 + 64 + lane] = k1;
  float lp = q0 * k0 + q1 * k1;
#pragma unroll
  for (int d = 1; d < 64; d <<= 1) lp += __shfl_xor(lp, d);
  if (lane == 0) lpos[b] = lp;
}

// ---------------- queue InfoNCE partials: per (chunk of 256 rows, b): (max, sumexp) ----------------
__global__ __launch_bounds__(256) void k_queue_nce(const float* __restrict__ queue,
                                                   const float* __restrict__ qg,
                                                   float* __restrict__ pm, float* __restrict__ ps) {
  __shared__ float qs[1024];
  int tid = threadIdx.x;
  for (int i = tid; i < 1024; i += 256) qs[i] = qg[i];
  __syncthreads();
  int r = blockIdx.x * 256 + tid;
  const float* qr = queue + (size_t)r * 128;
  float a[8] = {0, 0, 0, 0, 0, 0, 0, 0};
  for (int j = 0; j < 128; j += 4) {
    float4 v = *(const float4*)(const void*)(qr + j);
#pragma unroll
    for (int b = 0; b < 8; ++b)
      a[b] += v.x * qs[b * 128 + j] + v.y * qs[b * 128 + j + 1] +
              v.z * qs[b * 128 + j + 2] + v.w * qs[b * 128 + j + 3];
  }
  __shared__ float lm[8][4], lssum[8][4];
  int lane = tid & 63, w = tid >> 6;
#pragma unroll
  for (int b = 0; b < 8; ++b) {
    float m = a[b] * TAU_INV;
    float s = 1.0f;
#pragma unroll
    for (int d = 1; d < 64; d <<= 1) {
      float om = __shfl_xor(m, d), os = __shfl_xor(s, d);
      float nm = fmaxf(m, om);
      s = s * expf(m - nm) + os * expf(om - nm);
      m = nm;
    }
    if (lane == 0) { lm[b][w] = m; lssum[b][w] = s; }
  }
  __syncthreads();
  if (tid < 8) {
    int b = tid;
    float m = lm[b][0], s = lssum[b][0];
#pragma unroll
    for (int i = 1; i < 4; ++i) {
      float nm = fmaxf(m, lm[b][i]);
      s = s * expf(m - nm) + lssum[b][i] * expf(lm[b][i] - nm);
      m = nm;
    }
    pm[blockIdx.x * 8 + b] = m;
    ps[blockIdx.x * 8 + b] = s;
  }
}

// ---------------- dense-loss finalize: combine 49 lse partials, pos dot, block sum ----------------
__global__ void k_finalize_ld(const float* __restrict__ pmax, const float* __restrict__ psum,
                              const int* __restrict__ idxf, const float* __restrict__ qd,
                              const float* __restrict__ kd, float* __restrict__ ldpart) {
  int n = blockIdx.x * 128 + threadIdx.x;
  float m = pmax[(size_t)n * 49], s = psum[(size_t)n * 49];
  for (int j = 1; j < 49; ++j) {
    float om = pmax[(size_t)n * 49 + j], os = psum[(size_t)n * 49 + j];
    float nm = fmaxf(m, om);
    s = s * expf(m - nm) + os * expf(om - nm);
    m = nm;
  }
  float lse = m + logf(s);
  int b = n / 784;
  int mr = b * 784 + idxf[n];
  const float* qr = qd + (size_t)n * 128;
  const float* kr = kd + (size_t)mr * 128;
  float pos = 0.f;
  for (int p = 0; p < 128; ++p) pos += qr[p] * kr[p];
  pos *= TAU_INV;
  float diff = lse - pos;
#pragma unroll
  for (int d = 1; d < 64; d <<= 1) diff += __shfl_xor(diff, d);
  __shared__ float bs[2];
  int lane = threadIdx.x & 63, w = threadIdx.x >> 6;
  if (lane == 0) bs[w] = diff;
  __syncthreads();
  if (threadIdx.x == 0) ldpart[blockIdx.x] = bs[0] + bs[1];
}

// ---------------- final: combine queue partials + l_pos -> l_g; sum ldpart -> l_d; total ----------------
__global__ void k_final(const float* __restrict__ pm, const float* __restrict__ ps,
                        const float* __restrict__ lpos, const float* __restrict__ ldpart,
                        float* __restrict__ out) {
  int tid = threadIdx.x;
  int lane = tid & 63, w = tid >> 6;
  __shared__ float sm[4], ssh[4];
  float lg = 0.f;
  for (int b = 0; b < 8; ++b) {
    float m = pm[tid * 8 + b], s = ps[tid * 8 + b];
#pragma unroll
    for (int d = 1; d < 64; d <<= 1) {
      float om = __shfl_xor(m, d), os = __shfl_xor(s, d);
      float nm = fmaxf(m, om);
      s = s * expf(m - nm) + os * expf(om - nm);
      m = nm;
    }
    if (lane == 0) { sm[w] = m; ssh[w] = s; }
    __syncthreads();
    if (tid == 0) {
      float M = sm[0], S = ssh[0];
      for (int i = 1; i < 4; ++i) {
        float nm = fmaxf(M, sm[i]);
        S = S * expf(M - nm) + ssh[i] * expf(sm[i] - nm);
        M = nm;
      }
      float lp = lpos[b] * TAU_INV;
      float nm = fmaxf(M, lp);
      S = S * expf(M - nm) + expf(lp - nm);
      M = nm;
      lg += (M + logf(S)) - lp;
    }
    __syncthreads();
  }
  float v = (tid < 49) ? ldpart[tid] : 0.f;
#pragma unroll
  for (int d = 1; d < 64; d <<= 1) v += __shfl_xor(v, d);
  if (lane == 0) sm[w] = v;
  __syncthreads();
  if (tid == 0) {
    float ld = sm[0] + sm[1] + sm[2] + sm[3];
    out[0] = 0.5f * (lg * 0.125f) + 0.5f * (ld * (1.0f / 6272.0f));
  }
}

extern "C" void kernel_launch(void* const* d_in, const int* in_sizes, int n_in,
                              void* d_out, int out_size, void* d_ws, size_t ws_size,
                              hipStream_t stream) {
  (void)in_sizes; (void)n_in; (void)out_size; (void)ws_size;
  const float* feat_q = (const float*)d_in[0];
  const float* feat_k = (const float*)d_in[1];
  const float* Wg1 = (const float*)d_in[2];
  const float* bg1 = (const float*)d_in[3];
  const float* Wg2 = (const float*)d_in[4];
  const float* bg2 = (const float*)d_in[5];
  const float* Wd1 = (const float*)d_in[6];
  const float* bd1 = (const float*)d_in[7];
  const float* Wd2 = (const float*)d_in[8];
  const float* bd2 = (const float*)d_in[9];
  const float* mWg1 = (const float*)d_in[10];
  const float* mbg1 = (const float*)d_in[11];
  const float* mWg2 = (const float*)d_in[12];
  const float* mbg2 = (const float*)d_in[13];
  const float* mWd1 = (const float*)d_in[14];
  const float* mbd1 = (const float*)d_in[15];
  const float* mWd2 = (const float*)d_in[16];
  const float* mbd2 = (const float*)d_in[17];
  const float* queue = (const float*)d_in[18];
  float* out = (float*)d_out;

  char* ws = (char*)d_ws;
  size_t off = 0;
  auto alloc = [&](size_t bytes) -> void* {
    void* p = (void*)(ws + off);
    off += (bytes + 255) & ~(size_t)255;
    return p;
  };

  ushort* featq_bf = (ushort*)alloc(6272ull * 1024 * 2);
  ushort* featk_bf = (ushort*)alloc(6272ull * 1024 * 2);
  ushort* Wd1t = (ushort*)alloc(2048ull * 1024 * 2);
  ushort* mWd1t = (ushort*)alloc(2048ull * 1024 * 2);
  ushort* Wd2t = (ushort*)alloc(128ull * 2048 * 2);
  ushort* mWd2t = (ushort*)alloc(128ull * 2048 * 2);
  ushort* h_bf = (ushort*)alloc(6272ull * 2048 * 2);
  float* raw = (float*)alloc(6272ull * 128 * 4);
  float* qd = (float*)alloc(6272ull * 128 * 4);
  float* kd = (float*)alloc(6272ull * 128 * 4);
  ushort* qd_bf = (ushort*)alloc(6272ull * 128 * 2);
  ushort* kd_bf = (ushort*)alloc(6272ull * 128 * 2);
  ushort* matched_bf = (ushort*)alloc(6272ull * 128 * 2);
  float* pmax = (float*)alloc(6272ull * 49 * 4);
  float* psum = (float*)alloc(6272ull * 49 * 4);
  float* pval = (float*)alloc(6272ull * 7 * 4);
  int* pidx = (int*)alloc(6272ull * 7 * 4);
  int* idxf = (int*)alloc(6272ull * 4);
  float* gq = (float*)alloc(8ull * 1024 * 4);
  float* gk = (float*)alloc(8ull * 1024 * 4);
  float* hgq = (float*)alloc(8ull * 2048 * 4);
  float* hgk = (float*)alloc(8ull * 2048 * 4);
  float* qg_raw = (float*)alloc(8ull * 128 * 4);
  float* kg_raw = (float*)alloc(8ull * 128 * 4);
  float* qg = (float*)alloc(8ull * 128 * 4);
  float* kg = (float*)alloc(8ull * 128 * 4);
  float* l_pos = (float*)alloc(8ull * 4);
  float* qpart_m = (float*)alloc(256ull * 8 * 4);
  float* qpart_s = (float*)alloc(256ull * 8 * 4);
  float* ldpart = (float*)alloc(49ull * 4);

  // convert & transpose
  k_cvt_bf16<<<6272, 256, 0, stream>>>(feat_q, featq_bf, 1605632);
  k_cvt_bf16<<<6272, 256, 0, stream>>>(feat_k, featk_bf, 1605632);
  k_transpose_cvt<<<dim3(64, 32), 256, 0, stream>>>(Wd1, Wd1t, 1024, 2048);
  k_transpose_cvt<<<dim3(64, 32), 256, 0, stream>>>(mWd1, mWd1t, 1024, 2048);
  k_transpose_cvt<<<dim3(4, 64), 256, 0, stream>>>(Wd2, Wd2t, 2048, 128);
  k_transpose_cvt<<<dim3(4, 64), 256, 0, stream>>>(mWd2, mWd2t, 2048, 128);

  // dense head, student
  k_gemm_abt<0><<<dim3(16, 49, 1), 256, 0, stream>>>(featq_bf, Wd1t, bd1, h_bf, nullptr,
                                                     6272, 2048, 1024, 2048, 0, 0.f, 0, 0);
  k_gemm_abt<1><<<dim3(1, 49, 1), 256, 0, stream>>>(h_bf, Wd2t, bd2, raw, nullptr,
                                                    6272, 128, 2048, 128, 0, 0.f, 0, 0);
  k_l2n_rows<<<1568, 256, 0, stream>>>(raw, qd, qd_bf, 6272);

  // dense head, momentum
  k_gemm_abt<0><<<dim3(16, 49, 1), 256, 0, stream>>>(featk_bf, mWd1t, mbd1, h_bf, nullptr,
                                                     6272, 2048, 1024, 2048, 0, 0.f, 0, 0);
  k_gemm_abt<1><<<dim3(1, 49, 1), 256, 0, stream>>>(h_bf, mWd2t, mbd2, raw, nullptr,
                                                    6272, 128, 2048, 128, 0, 0.f, 0, 0);
  k_l2n_rows<<<1568, 256, 0, stream>>>(raw, kd, kd_bf, 6272);

  // dense correspondence (batched argmax)
  k_gemm_abt<3><<<dim3(7, 7, 8), 256, 0, stream>>>(qd_bf, kd_bf, nullptr, pval, pidx,
                                                   784, 784, 128, 0, 7, 0.f,
                                                   784l * 128, 784l * 128);
  k_argmax_gather<<<6272, 64, 0, stream>>>(pval, pidx, kd_bf, matched_bf, idxf);

  // dense InfoNCE lse partials (6272 x 6272)
  k_gemm_abt<2><<<dim3(49, 49, 1), 256, 0, stream>>>(qd_bf, matched_bf, nullptr, pmax, psum,
                                                     6272, 6272, 128, 0, 49, TAU_INV, 0, 0);

  // global head (fp32)
  k_gpool<<<dim3(4, 8), 256, 0, stream>>>(feat_q, gq);
  k_gpool<<<dim3(4, 8), 256, 0, stream>>>(feat_k, gk);
  k_dense1<<<dim3(8, 8), 256, 0, stream>>>(gq, Wg1, bg1, hgq);
  k_dense1<<<dim3(8, 8), 256, 0, stream>>>(gk, mWg1, mbg1, hgk);
  k_dense2<<<8, 128, 0, stream>>>(hgq, Wg2, bg2, qg_raw);
  k_dense2<<<8, 128, 0, stream>>>(hgk, mWg2, mbg2, kg_raw);
  k_norm_small<<<8, 64, 0, stream>>>(qg_raw, kg_raw, qg, kg, l_pos);

  // queue InfoNCE
  k_queue_nce<<<256, 256, 0, stream>>>(queue, qg, qpart_m, qpart_s);

  // finalize losses
  k_finalize_ld<<<49, 128, 0, stream>>>(pmax, psum, idxf, qd, kd, ldpart);
  k_final<<<1, 256, 0, stream>>>(qpart_m, qpart_s, l_pos, ldpart, out);
}

// Round 2
// 409.238 us; speedup vs baseline: 1.9473x; 1.9473x over previous
//
#include <hip/hip_runtime.h>

#define TAU_INV 5.0f

using ushort = unsigned short;
typedef __attribute__((ext_vector_type(8))) short s16x8;
typedef __attribute__((ext_vector_type(4))) float f32x4;

static __device__ __forceinline__ ushort f2bf(float x) {
  unsigned u = __float_as_uint(x);
  return (ushort)((u + 0x7fffu + ((u >> 16) & 1u)) >> 16);
}

// ---------------- fused f32->bf16 convert + partial channel pool ----------------
// grid (28 pchunks, 8 batch), block 256 (each thread owns 4 consecutive channels)
__global__ void k_cvt_pool(const float* __restrict__ feat, ushort* __restrict__ obf,
                           float* __restrict__ gpart) {
  int b = blockIdx.y, pc = blockIdx.x, t = threadIdx.x;
  const float* fp = feat + ((size_t)b * 784 + (size_t)pc * 28) * 1024;
  ushort* op = obf + ((size_t)b * 784 + (size_t)pc * 28) * 1024;
  float4 acc = {0.f, 0.f, 0.f, 0.f};
  for (int p = 0; p < 28; ++p) {
    float4 v = ((const float4*)(fp + (size_t)p * 1024))[t];
    acc.x += v.x; acc.y += v.y; acc.z += v.z; acc.w += v.w;
    ushort4 r;
    r.x = f2bf(v.x); r.y = f2bf(v.y); r.z = f2bf(v.z); r.w = f2bf(v.w);
    ((ushort4*)(op + (size_t)p * 1024))[t] = r;
  }
  ((float4*)(gpart + ((size_t)b * 28 + pc) * 1024))[t] = acc;
}

// g[b][c] = mean over 28 partials
__global__ void k_gpool_fin(const float* __restrict__ gpart, float* __restrict__ g) {
  int idx = blockIdx.x * 256 + threadIdx.x;   // 8192 total
  int b = idx >> 10, c = idx & 1023;
  float s = 0.f;
#pragma unroll
  for (int pc = 0; pc < 28; ++pc) s += gpart[((size_t)b * 28 + pc) * 1024 + c];
  g[idx] = s * (1.0f / 784.0f);
}

// part1[ks][b][d] partial of g[8,1024] @ W[1024,2048]; grid (8 dchunk, 16 kslice), block 256
__global__ void k_dense1_part(const float* __restrict__ g, const float* __restrict__ W,
                              float* __restrict__ part1) {
  int d = blockIdx.x * 256 + threadIdx.x;
  int k0 = blockIdx.y * 64;
  __shared__ float gs[512];
  for (int i = threadIdx.x; i < 512; i += 256) gs[i] = g[(i >> 6) * 1024 + k0 + (i & 63)];
  __syncthreads();
  float acc[8] = {};
  for (int kk = 0; kk < 64; ++kk) {
    float w = W[(size_t)(k0 + kk) * 2048 + d];
#pragma unroll
    for (int b = 0; b < 8; ++b) acc[b] += gs[b * 64 + kk] * w;
  }
#pragma unroll
  for (int b = 0; b < 8; ++b) part1[((size_t)blockIdx.y * 8 + b) * 2048 + d] = acc[b];
}

// h[b][d] = relu(bias + sum of 16 partials); 64 blocks x 256
__global__ void k_dense1_fin(const float* __restrict__ part1, const float* __restrict__ bias,
                             float* __restrict__ h) {
  int idx = blockIdx.x * 256 + threadIdx.x;   // 16384
  int b = idx >> 11, d = idx & 2047;
  float s = bias[d];
#pragma unroll
  for (int ks = 0; ks < 16; ++ks) s += part1[((size_t)ks * 8 + b) * 2048 + d];
  h[idx] = fmaxf(s, 0.f);
}

// part2[ks][b][p] partial of h[8,2048] @ W2[2048,128]; grid 32 kslices, block 128
__global__ void k_dense2_part(const float* __restrict__ h, const float* __restrict__ W2,
                              float* __restrict__ part2) {
  int d = threadIdx.x;
  int k0 = blockIdx.x * 64;
  __shared__ float hs[512];
  for (int i = threadIdx.x; i < 512; i += 128) hs[i] = h[(i >> 6) * 2048 + k0 + (i & 63)];
  __syncthreads();
  float acc[8] = {};
  for (int kk = 0; kk < 64; ++kk) {
    float w = W2[(size_t)(k0 + kk) * 128 + d];
#pragma unroll
    for (int b = 0; b < 8; ++b) acc[b] += hs[b * 64 + kk] * w;
  }
#pragma unroll
  for (int b = 0; b < 8; ++b) part2[((size_t)blockIdx.x * 8 + b) * 128 + d] = acc[b];
}

// per-batch: sum 32 partials + bias for q and k, l2-normalize, l_pos; grid 8, block 64
__global__ void k_head_fin(const float* __restrict__ p2q, const float* __restrict__ p2k,
                           const float* __restrict__ bq, const float* __restrict__ bk,
                           float* __restrict__ qg, float* __restrict__ kg,
                           float* __restrict__ lpos) {
  int b = blockIdx.x, lane = threadIdx.x;
  float q0 = bq[lane], q1 = bq[lane + 64];
  float k0 = bk[lane], k1 = bk[lane + 64];
#pragma unroll
  for (int s = 0; s < 32; ++s) {
    size_t base = ((size_t)s * 8 + b) * 128;
    q0 += p2q[base + lane]; q1 += p2q[base + lane + 64];
    k0 += p2k[base + lane]; k1 += p2k[base + lane + 64];
  }
  float sq = q0 * q0 + q1 * q1, sk = k0 * k0 + k1 * k1;
#pragma unroll
  for (int d = 1; d < 64; d <<= 1) { sq += __shfl_xor(sq, d); sk += __shfl_xor(sk, d); }
  float rq = 1.0f / sqrtf(fmaxf(sq, 1e-12f));
  float rk = 1.0f / sqrtf(fmaxf(sk, 1e-12f));
  q0 *= rq; q1 *= rq; k0 *= rk; k1 *= rk;
  qg[b * 128 + lane] = q0; qg[b * 128 + 64 + lane] = q1;
  kg[b * 128 + lane] = k0; kg[b * 128 + 64 + lane] = k1;
  float lp = q0 * k0 + q1 * k1;
#pragma unroll
  for (int d = 1; d < 64; d <<= 1) lp += __shfl_xor(lp, d);
  if (lane == 0) lpos[b] = lp;
}

// ---------------- transpose + convert: W[K,N] f32 -> Wt[N,K] bf16 ----------------
__global__ void k_transpose_cvt(const float* __restrict__ W, ushort* __restrict__ Wt, int K, int N) {
  __shared__ float tile[32][33];
  int n0 = blockIdx.x * 32, k0 = blockIdx.y * 32;
  int tx = threadIdx.x & 31, ty = threadIdx.x >> 5;
#pragma unroll
  for (int i = 0; i < 32; i += 8)
    tile[ty + i][tx] = W[(size_t)(k0 + ty + i) * N + n0 + tx];
  __syncthreads();
#pragma unroll
  for (int i = 0; i < 32; i += 8)
    Wt[(size_t)(n0 + ty + i) * K + k0 + tx] = f2bf(tile[tx][ty + i]);
}

// ---------------- MFMA GEMM: C = A[M,*lda] @ B[N,*ldb]^T over Kloop, bf16 in / f32 acc ----
// EPI 0: +bias, relu, store bf16    EPI 2: per-row online (max,sumexp)*scale partials
// EPI 3: per-row (max,argmax)       EPI 4: store raw f32 at slice offset bz*ntiles
template <int EPI>
__global__ __launch_bounds__(256) void k_gemm_abt(
    const ushort* __restrict__ A, const ushort* __restrict__ B,
    const float* __restrict__ bias, void* __restrict__ o0, void* __restrict__ o1,
    int Mvalid, int Nvalid, int Kloop, int lda, int ldb, int ldOut, int ntiles,
    float scale, long sA, long sB) {
  __shared__ unsigned char smem[32768];
  unsigned char* As = smem;
  unsigned char* Bs = smem + 16384;
  const int tid = threadIdx.x;
  const int bx = blockIdx.x, by = blockIdx.y, bz = blockIdx.z;
  const ushort* Ab = A + (size_t)bz * sA;
  const ushort* Bb = B + (size_t)bz * sB;
  const int mBase = by * 128, nBase = bx * 128;
  const int lane = tid & 63;
  const int wid = tid >> 6;
  const int wm = wid >> 1, wn = wid & 1;
  const int lg = lane >> 4, li = lane & 15;
  f32x4 acc[4][4] = {};

  for (int k0 = 0; k0 < Kloop; k0 += 64) {
    __syncthreads();
#pragma unroll
    for (int i = 0; i < 4; ++i) {
      int q = tid + i * 256;
      int row = q >> 3, kc = (q & 7) << 3;
      int sw = ((kc << 1) ^ ((row & 7) << 4));
      float4 va = {0.f, 0.f, 0.f, 0.f}, vb = {0.f, 0.f, 0.f, 0.f};
      if (mBase + row < Mvalid) va = *(const float4*)(const void*)(Ab + (size_t)(mBase + row) * lda + k0 + kc);
      if (nBase + row < Nvalid) vb = *(const float4*)(const void*)(Bb + (size_t)(nBase + row) * ldb + k0 + kc);
      *(float4*)(void*)(As + row * 128 + sw) = va;
      *(float4*)(void*)(Bs + row * 128 + sw) = vb;
    }
    __syncthreads();
#pragma unroll
    for (int ks = 0; ks < 2; ++ks) {
      s16x8 af[4], bfr[4];
#pragma unroll
      for (int mi = 0; mi < 4; ++mi) {
        int r = wm * 64 + mi * 16 + li;
        af[mi] = *(const s16x8*)(const void*)(As + r * 128 + ((ks * 64 + lg * 16) ^ ((r & 7) << 4)));
      }
#pragma unroll
      for (int ni = 0; ni < 4; ++ni) {
        int c = wn * 64 + ni * 16 + li;
        bfr[ni] = *(const s16x8*)(const void*)(Bs + c * 128 + ((ks * 64 + lg * 16) ^ ((c & 7) << 4)));
      }
#pragma unroll
      for (int mi = 0; mi < 4; ++mi)
#pragma unroll
        for (int ni = 0; ni < 4; ++ni)
          acc[mi][ni] = __builtin_amdgcn_mfma_f32_16x16x32_bf16(af[mi], bfr[ni], acc[mi][ni], 0, 0, 0);
    }
  }

  if constexpr (EPI == 0 || EPI == 4) {
#pragma unroll
    for (int mi = 0; mi < 4; ++mi)
#pragma unroll
      for (int ni = 0; ni < 4; ++ni) {
        int c = nBase + wn * 64 + ni * 16 + li;
#pragma unroll
        for (int rg = 0; rg < 4; ++rg) {
          int r = mBase + wm * 64 + mi * 16 + lg * 4 + rg;
          if (r < Mvalid && c < Nvalid) {
            if constexpr (EPI == 0) {
              float v = fmaxf(acc[mi][ni][rg] + bias[c], 0.f);
              ((ushort*)o0)[(size_t)r * ldOut + c] = f2bf(v);
            } else {
              ((float*)o0)[(size_t)bz * ntiles + (size_t)r * ldOut + c] = acc[mi][ni][rg];
            }
          }
        }
      }
  } else if constexpr (EPI == 2) {
    __syncthreads();
    float* redm = (float*)(void*)smem;   // [128][2]
    float* reds = redm + 256;
#pragma unroll
    for (int mi = 0; mi < 4; ++mi)
#pragma unroll
      for (int rg = 0; rg < 4; ++rg) {
        float v0 = acc[mi][0][rg] * scale;
        float v1 = acc[mi][1][rg] * scale;
        float v2 = acc[mi][2][rg] * scale;
        float v3 = acc[mi][3][rg] * scale;
        float m = fmaxf(fmaxf(v0, v1), fmaxf(v2, v3));
        float s = expf(v0 - m) + expf(v1 - m) + expf(v2 - m) + expf(v3 - m);
#pragma unroll
        for (int d = 1; d < 16; d <<= 1) {
          float om = __shfl_xor(m, d);
          float os = __shfl_xor(s, d);
          float nm = fmaxf(m, om);
          s = s * expf(m - nm) + os * expf(om - nm);
          m = nm;
        }
        int rl = wm * 64 + mi * 16 + lg * 4 + rg;
        if (li == 0) { redm[rl * 2 + wn] = m; reds[rl * 2 + wn] = s; }
      }
    __syncthreads();
    if (tid < 128) {
      float m0 = redm[tid * 2], m1 = redm[tid * 2 + 1];
      float s0 = reds[tid * 2], s1 = reds[tid * 2 + 1];
      float m = fmaxf(m0, m1);
      float s = s0 * expf(m0 - m) + s1 * expf(m1 - m);
      size_t idx = (size_t)(mBase + tid) * ntiles + bx;
      ((float*)o0)[idx] = m;
      ((float*)o1)[idx] = s;
    }
  } else if constexpr (EPI == 3) {
    __syncthreads();
    float* redv = (float*)(void*)smem;          // [128][2]
    int* redi = (int*)(void*)(smem + 1024);
#pragma unroll
    for (int mi = 0; mi < 4; ++mi)
#pragma unroll
      for (int rg = 0; rg < 4; ++rg) {
        float bv = -3.4e38f;
        int bi = 0x7fffffff;
#pragma unroll
        for (int ni = 0; ni < 4; ++ni) {
          int c = nBase + wn * 64 + ni * 16 + li;
          float v = (c < Nvalid) ? acc[mi][ni][rg] : -3.4e38f;
          if (v > bv || (v == bv && c < bi)) { bv = v; bi = c; }
        }
#pragma unroll
        for (int d = 1; d < 16; d <<= 1) {
          float ov = __shfl_xor(bv, d);
          int oi = __shfl_xor(bi, d);
          if (ov > bv || (ov == bv && oi < bi)) { bv = ov; bi = oi; }
        }
        int rl = wm * 64 + mi * 16 + lg * 4 + rg;
        if (li == 0) { redv[rl * 2 + wn] = bv; redi[rl * 2 + wn] = bi; }
      }
    __syncthreads();
    if (tid < 128) {
      int r = mBase + tid;
      if (r < Mvalid) {
        float v0 = redv[tid * 2], v1 = redv[tid * 2 + 1];
        int i0 = redi[tid * 2], i1 = redi[tid * 2 + 1];
        float v = v0; int bi2 = i0;
        if (v1 > v || (v1 == v && i1 < bi2)) { v = v1; bi2 = i1; }
        size_t idx = (size_t)(bz * Mvalid + r) * ntiles + bx;
        ((float*)o0)[idx] = v;
        ((int*)o1)[idx] = bi2;
      }
    }
  }
}

// ---------------- sum 4 K-slice partials + bias, l2-normalize, write f32 + bf16 --------
__global__ void k_l2n_rows(const float* __restrict__ part, const float* __restrict__ bias,
                           float* __restrict__ of, ushort* __restrict__ ob, int rows) {
  int row = blockIdx.x * 4 + (threadIdx.x >> 6);
  int lane = threadIdx.x & 63;
  if (row >= rows) return;
  size_t i0 = (size_t)row * 128 + lane;
  const size_t SL = 802816;  // 6272*128
  float v0 = bias[lane]      + part[i0]      + part[SL + i0]      + part[2 * SL + i0]      + part[3 * SL + i0];
  float v1 = bias[lane + 64] + part[i0 + 64] + part[SL + i0 + 64] + part[2 * SL + i0 + 64] + part[3 * SL + i0 + 64];
  float ss = v0 * v0 + v1 * v1;
#pragma unroll
  for (int d = 1; d < 64; d <<= 1) ss += __shfl_xor(ss, d);
  float r = 1.0f / sqrtf(fmaxf(ss, 1e-12f));
  of[i0] = v0 * r;
  of[i0 + 64] = v1 * r;
  ob[i0] = f2bf(v0 * r);
  ob[i0 + 64] = f2bf(v1 * r);
}

// ---------------- argmax finalize over 7 col-tiles + gather matched row ----------------
__global__ void k_argmax_gather(const float* __restrict__ pval, const int* __restrict__ pidx,
                                const ushort* __restrict__ kd_bf, ushort* __restrict__ matched_bf,
                                int* __restrict__ idxf) {
  int n = blockIdx.x;
  int b = n / 784;
  float bv = pval[(size_t)n * 7];
  int bi = pidx[(size_t)n * 7];
#pragma unroll
  for (int t = 1; t < 7; ++t) {
    float v = pval[(size_t)n * 7 + t];
    int i2 = pidx[(size_t)n * 7 + t];
    if (v > bv) { bv = v; bi = i2; }
  }
  int lane = threadIdx.x;
  if (lane == 0) idxf[n] = bi;
  const ushort* src = kd_bf + (size_t)(b * 784 + bi) * 128;
  ushort* dst = matched_bf + (size_t)n * 128;
  dst[lane] = src[lane];
  dst[lane + 64] = src[lane + 64];
}

// ---------------- queue InfoNCE partials ----------------
__global__ __launch_bounds__(256) void k_queue_nce(const float* __restrict__ queue,
                                                   const float* __restrict__ qg,
                                                   float* __restrict__ pm, float* __restrict__ ps) {
  __shared__ float qs[1024];
  int tid = threadIdx.x;
  for (int i = tid; i < 1024; i += 256) qs[i] = qg[i];
  __syncthreads();
  int r = blockIdx.x * 256 + tid;
  const float* qr = queue + (size_t)r * 128;
  float a[8] = {0, 0, 0, 0, 0, 0, 0, 0};
  for (int j = 0; j < 128; j += 4) {
    float4 v = *(const float4*)(const void*)(qr + j);
#pragma unroll
    for (int b = 0; b < 8; ++b)
      a[b] += v.x * qs[b * 128 + j] + v.y * qs[b * 128 + j + 1] +
              v.z * qs[b * 128 + j + 2] + v.w * qs[b * 128 + j + 3];
  }
  __shared__ float lm[8][4], lssum[8][4];
  int lane = tid & 63, w = tid >> 6;
#pragma unroll
  for (int b = 0; b < 8; ++b) {
    float m = a[b] * TAU_INV;
    float s = 1.0f;
#pragma unroll
    for (int d = 1; d < 64; d <<= 1) {
      float om = __shfl_xor(m, d), os = __shfl_xor(s, d);
      float nm = fmaxf(m, om);
      s = s * expf(m - nm) + os * expf(om - nm);
      m = nm;
    }
    if (lane == 0) { lm[b][w] = m; lssum[b][w] = s; }
  }
  __syncthreads();
  if (tid < 8) {
    int b = tid;
    float m = lm[b][0], s = lssum[b][0];
#pragma unroll
    for (int i = 1; i < 4; ++i) {
      float nm = fmaxf(m, lm[b][i]);
      s = s * expf(m - nm) + lssum[b][i] * expf(lm[b][i] - nm);
      m = nm;
    }
    pm[blockIdx.x * 8 + b] = m;
    ps[blockIdx.x * 8 + b] = s;
  }
}

// ---------------- per-row LSE combine + pos dot, wave per row; grid 1568 x 256 ---------
__global__ void k_row_lse(const float* __restrict__ pmax, const float* __restrict__ psum,
                          const int* __restrict__ idxf, const float* __restrict__ qd,
                          const float* __restrict__ kd, float* __restrict__ diff) {
  int n = blockIdx.x * 4 + (threadIdx.x >> 6);
  int lane = threadIdx.x & 63;
  float m = -3.4e38f, s = 0.f;
  if (lane < 49) {
    m = pmax[(size_t)n * 49 + lane];
    s = psum[(size_t)n * 49 + lane];
  }
#pragma unroll
  for (int d = 1; d < 64; d <<= 1) {
    float om = __shfl_xor(m, d), os = __shfl_xor(s, d);
    float nm = fmaxf(m, om);
    s = s * expf(m - nm) + os * expf(om - nm);
    m = nm;
  }
  int b = n / 784;
  int mr = b * 784 + idxf[n];
  float pos = qd[(size_t)n * 128 + lane] * kd[(size_t)mr * 128 + lane] +
              qd[(size_t)n * 128 + 64 + lane] * kd[(size_t)mr * 128 + 64 + lane];
#pragma unroll
  for (int d = 1; d < 64; d <<= 1) pos += __shfl_xor(pos, d);
  if (lane == 0) diff[n] = (m + logf(s)) - pos * TAU_INV;
}

// ---------------- final combine ----------------
__global__ void k_final(const float* __restrict__ pm, const float* __restrict__ ps,
                        const float* __restrict__ lpos, const float* __restrict__ diff,
                        float* __restrict__ out) {
  int tid = threadIdx.x;
  int lane = tid & 63, w = tid >> 6;
  __shared__ float sm[4], ssh[4];
  float lg = 0.f;
  for (int b = 0; b < 8; ++b) {
    float m = pm[tid * 8 + b], s = ps[tid * 8 + b];
#pragma unroll
    for (int d = 1; d < 64; d <<= 1) {
      float om = __shfl_xor(m, d), os = __shfl_xor(s, d);
      float nm = fmaxf(m, om);
      s = s * expf(m - nm) + os * expf(om - nm);
      m = nm;
    }
    if (lane == 0) { sm[w] = m; ssh[w] = s; }
    __syncthreads();
    if (tid == 0) {
      float M = sm[0], S = ssh[0];
      for (int i = 1; i < 4; ++i) {
        float nm = fmaxf(M, sm[i]);
        S = S * expf(M - nm) + ssh[i] * expf(sm[i] - nm);
        M = nm;
      }
      float lp = lpos[b] * TAU_INV;
      float nm = fmaxf(M, lp);
      S = S * expf(M - nm) + expf(lp - nm);
      M = nm;
      lg += (M + logf(S)) - lp;
    }
    __syncthreads();
  }
  float v = 0.f;
  for (int i = tid; i < 6272; i += 256) v += diff[i];
#pragma unroll
  for (int d = 1; d < 64; d <<= 1) v += __shfl_xor(v, d);
  if (lane == 0) sm[w] = v;
  __syncthreads();
  if (tid == 0) {
    float ld = sm[0] + sm[1] + sm[2] + sm[3];
    out[0] = 0.5f * (lg * 0.125f) + 0.5f * (ld * (1.0f / 6272.0f));
  }
}

extern "C" void kernel_launch(void* const* d_in, const int* in_sizes, int n_in,
                              void* d_out, int out_size, void* d_ws, size_t ws_size,
                              hipStream_t stream) {
  (void)in_sizes; (void)n_in; (void)out_size; (void)ws_size;
  const float* feat_q = (const float*)d_in[0];
  const float* feat_k = (const float*)d_in[1];
  const float* Wg1 = (const float*)d_in[2];
  const float* bg1 = (const float*)d_in[3];
  const float* Wg2 = (const float*)d_in[4];
  const float* bg2 = (const float*)d_in[5];
  const float* Wd1 = (const float*)d_in[6];
  const float* bd1 = (const float*)d_in[7];
  const float* Wd2 = (const float*)d_in[8];
  const float* bd2 = (const float*)d_in[9];
  const float* mWg1 = (const float*)d_in[10];
  const float* mbg1 = (const float*)d_in[11];
  const float* mWg2 = (const float*)d_in[12];
  const float* mbg2 = (const float*)d_in[13];
  const float* mWd1 = (const float*)d_in[14];
  const float* mbd1 = (const float*)d_in[15];
  const float* mWd2 = (const float*)d_in[16];
  const float* mbd2 = (const float*)d_in[17];
  const float* queue = (const float*)d_in[18];
  float* out = (float*)d_out;

  char* ws = (char*)d_ws;
  size_t off = 0;
  auto alloc = [&](size_t bytes) -> void* {
    void* p = (void*)(ws + off);
    off += (bytes + 255) & ~(size_t)255;
    return p;
  };

  ushort* featq_bf = (ushort*)alloc(6272ull * 1024 * 2);
  ushort* featk_bf = (ushort*)alloc(6272ull * 1024 * 2);
  ushort* Wd1t = (ushort*)alloc(2048ull * 1024 * 2);
  ushort* mWd1t = (ushort*)alloc(2048ull * 1024 * 2);
  ushort* Wd2t = (ushort*)alloc(128ull * 2048 * 2);
  ushort* mWd2t = (ushort*)alloc(128ull * 2048 * 2);
  ushort* h_bf = (ushort*)alloc(6272ull * 2048 * 2);
  float* e2part = (float*)alloc(4ull * 6272 * 128 * 4);
  float* qd = (float*)alloc(6272ull * 128 * 4);
  float* kd = (float*)alloc(6272ull * 128 * 4);
  ushort* qd_bf = (ushort*)alloc(6272ull * 128 * 2);
  ushort* kd_bf = (ushort*)alloc(6272ull * 128 * 2);
  ushort* matched_bf = (ushort*)alloc(6272ull * 128 * 2);
  float* pmax = (float*)alloc(6272ull * 49 * 4);
  float* psum = (float*)alloc(6272ull * 49 * 4);
  float* pval = (float*)alloc(6272ull * 7 * 4);
  int* pidx = (int*)alloc(6272ull * 7 * 4);
  int* idxf = (int*)alloc(6272ull * 4);
  float* gpart = (float*)alloc(8ull * 28 * 1024 * 4);
  float* gq = (float*)alloc(8ull * 1024 * 4);
  float* gk = (float*)alloc(8ull * 1024 * 4);
  float* part1 = (float*)alloc(16ull * 8 * 2048 * 4);
  float* hgq = (float*)alloc(8ull * 2048 * 4);
  float* hgk = (float*)alloc(8ull * 2048 * 4);
  float* part2q = (float*)alloc(32ull * 8 * 128 * 4);
  float* part2k = (float*)alloc(32ull * 8 * 128 * 4);
  float* qg = (float*)alloc(8ull * 128 * 4);
  float* kg = (float*)alloc(8ull * 128 * 4);
  float* l_pos = (float*)alloc(8ull * 4);
  float* qpart_m = (float*)alloc(256ull * 8 * 4);
  float* qpart_s = (float*)alloc(256ull * 8 * 4);
  float* diff = (float*)alloc(6272ull * 4);

  // fused convert + pool partials (q then k; gpart reused sequentially)
  k_cvt_pool<<<dim3(28, 8), 256, 0, stream>>>(feat_q, featq_bf, gpart);
  k_gpool_fin<<<32, 256, 0, stream>>>(gpart, gq);
  k_cvt_pool<<<dim3(28, 8), 256, 0, stream>>>(feat_k, featk_bf, gpart);
  k_gpool_fin<<<32, 256, 0, stream>>>(gpart, gk);

  // weight transposes
  k_transpose_cvt<<<dim3(64, 32), 256, 0, stream>>>(Wd1, Wd1t, 1024, 2048);
  k_transpose_cvt<<<dim3(64, 32), 256, 0, stream>>>(mWd1, mWd1t, 1024, 2048);
  k_transpose_cvt<<<dim3(4, 64), 256, 0, stream>>>(Wd2, Wd2t, 2048, 128);
  k_transpose_cvt<<<dim3(4, 64), 256, 0, stream>>>(mWd2, mWd2t, 2048, 128);

  // global head, student then momentum (part1/hg buffers sequential)
  k_dense1_part<<<dim3(8, 16), 256, 0, stream>>>(gq, Wg1, part1);
  k_dense1_fin<<<64, 256, 0, stream>>>(part1, bg1, hgq);
  k_dense2_part<<<32, 128, 0, stream>>>(hgq, Wg2, part2q);
  k_dense1_part<<<dim3(8, 16), 256, 0, stream>>>(gk, mWg1, part1);
  k_dense1_fin<<<64, 256, 0, stream>>>(part1, mbg1, hgk);
  k_dense2_part<<<32, 128, 0, stream>>>(hgk, mWg2, part2k);
  k_head_fin<<<8, 64, 0, stream>>>(part2q, part2k, bg2, mbg2, qg, kg, l_pos);

  // dense head, student
  k_gemm_abt<0><<<dim3(16, 49, 1), 256, 0, stream>>>(featq_bf, Wd1t, bd1, h_bf, nullptr,
                                                     6272, 2048, 1024, 1024, 1024, 2048, 0, 0.f, 0, 0);
  k_gemm_abt<4><<<dim3(1, 49, 4), 256, 0, stream>>>(h_bf, Wd2t, nullptr, e2part, nullptr,
                                                    6272, 128, 512, 2048, 2048, 128, 802816, 0.f, 512, 512);
  k_l2n_rows<<<1568, 256, 0, stream>>>(e2part, bd2, qd, qd_bf, 6272);

  // dense head, momentum
  k_gemm_abt<0><<<dim3(16, 49, 1), 256, 0, stream>>>(featk_bf, mWd1t, mbd1, h_bf, nullptr,
                                                     6272, 2048, 1024, 1024, 1024, 2048, 0, 0.f, 0, 0);
  k_gemm_abt<4><<<dim3(1, 49, 4), 256, 0, stream>>>(h_bf, mWd2t, nullptr, e2part, nullptr,
                                                    6272, 128, 512, 2048, 2048, 128, 802816, 0.f, 512, 512);
  k_l2n_rows<<<1568, 256, 0, stream>>>(e2part, mbd2, kd, kd_bf, 6272);

  // dense correspondence (batched argmax)
  k_gemm_abt<3><<<dim3(7, 7, 8), 256, 0, stream>>>(qd_bf, kd_bf, nullptr, pval, pidx,
                                                   784, 784, 128, 128, 128, 0, 7, 0.f,
                                                   784l * 128, 784l * 128);
  k_argmax_gather<<<6272, 64, 0, stream>>>(pval, pidx, kd_bf, matched_bf, idxf);

  // dense InfoNCE lse partials (6272 x 6272)
  k_gemm_abt<2><<<dim3(49, 49, 1), 256, 0, stream>>>(qd_bf, matched_bf, nullptr, pmax, psum,
                                                     6272, 6272, 128, 128, 128, 0, 49, TAU_INV, 0, 0);

  // queue InfoNCE
  k_queue_nce<<<256, 256, 0, stream>>>(queue, qg, qpart_m, qpart_s);

  // finalize losses
  k_row_lse<<<1568, 256, 0, stream>>>(pmax, psum, idxf, qd, kd, diff);
  k_final<<<1, 256, 0, stream>>>(qpart_m, qpart_s, l_pos, diff, out);
}

// Round 3
// 375.537 us; speedup vs baseline: 2.1221x; 1.0897x over previous
//
#include <hip/hip_runtime.h>
#include <cstdint>

#define TAU_INV 5.0f

using ushort = unsigned short;
typedef __attribute__((ext_vector_type(8))) short s16x8;
typedef __attribute__((ext_vector_type(4))) float f32x4;

static __device__ __forceinline__ ushort f2bf(float x) {
  unsigned u = __float_as_uint(x);
  return (ushort)((u + 0x7fffu + ((u >> 16) & 1u)) >> 16);
}

static __device__ __forceinline__ void gload_lds16(const void* g, void* l) {
  __builtin_amdgcn_global_load_lds(
      reinterpret_cast<const __attribute__((address_space(1))) void*>(
          reinterpret_cast<uintptr_t>(g)),
      reinterpret_cast<__attribute__((address_space(3))) void*>(
          (unsigned)reinterpret_cast<uintptr_t>(l)),
      16, 0, 0);
}

// ---------------- fused f32->bf16 convert + partial channel pool ----------------
// grid (112 pchunks of 7 pixels, 8 batch), block 256 (thread owns 4 channels)
__global__ void k_cvt_pool(const float* __restrict__ feat, ushort* __restrict__ obf,
                           float* __restrict__ gpart) {
  int b = blockIdx.y, pc = blockIdx.x, t = threadIdx.x;
  const float* fp = feat + ((size_t)b * 784 + (size_t)pc * 7) * 1024;
  ushort* op = obf + ((size_t)b * 784 + (size_t)pc * 7) * 1024;
  float4 acc = {0.f, 0.f, 0.f, 0.f};
#pragma unroll
  for (int p = 0; p < 7; ++p) {
    float4 v = ((const float4*)(fp + (size_t)p * 1024))[t];
    acc.x += v.x; acc.y += v.y; acc.z += v.z; acc.w += v.w;
    ushort4 r;
    r.x = f2bf(v.x); r.y = f2bf(v.y); r.z = f2bf(v.z); r.w = f2bf(v.w);
    ((ushort4*)(op + (size_t)p * 1024))[t] = r;
  }
  ((float4*)(gpart + ((size_t)b * 112 + pc) * 1024))[t] = acc;
}

// g[b][c] = mean over 112 partials
__global__ void k_gpool_fin(const float* __restrict__ gpart, float* __restrict__ g) {
  int idx = blockIdx.x * 256 + threadIdx.x;   // 8192 total
  int b = idx >> 10, c = idx & 1023;
  float s = 0.f;
#pragma unroll 4
  for (int pc = 0; pc < 112; ++pc) s += gpart[((size_t)b * 112 + pc) * 1024 + c];
  g[idx] = s * (1.0f / 784.0f);
}

// part1[ks][b][d] partial of g[8,1024] @ W[1024,2048]; grid (8 dchunk, 16 kslice), block 256
__global__ void k_dense1_part(const float* __restrict__ g, const float* __restrict__ W,
                              float* __restrict__ part1) {
  int d = blockIdx.x * 256 + threadIdx.x;
  int k0 = blockIdx.y * 64;
  __shared__ float gs[512];
  for (int i = threadIdx.x; i < 512; i += 256) gs[i] = g[(i >> 6) * 1024 + k0 + (i & 63)];
  __syncthreads();
  float acc[8] = {};
  for (int kk = 0; kk < 64; ++kk) {
    float w = W[(size_t)(k0 + kk) * 2048 + d];
#pragma unroll
    for (int b = 0; b < 8; ++b) acc[b] += gs[b * 64 + kk] * w;
  }
#pragma unroll
  for (int b = 0; b < 8; ++b) part1[((size_t)blockIdx.y * 8 + b) * 2048 + d] = acc[b];
}

// h[b][d] = relu(bias + sum of 16 partials); 64 blocks x 256
__global__ void k_dense1_fin(const float* __restrict__ part1, const float* __restrict__ bias,
                             float* __restrict__ h) {
  int idx = blockIdx.x * 256 + threadIdx.x;   // 16384
  int b = idx >> 11, d = idx & 2047;
  float s = bias[d];
#pragma unroll
  for (int ks = 0; ks < 16; ++ks) s += part1[((size_t)ks * 8 + b) * 2048 + d];
  h[idx] = fmaxf(s, 0.f);
}

// part2[ks][b][p] partial of h[8,2048] @ W2[2048,128]; grid 32 kslices, block 128
__global__ void k_dense2_part(const float* __restrict__ h, const float* __restrict__ W2,
                              float* __restrict__ part2) {
  int d = threadIdx.x;
  int k0 = blockIdx.x * 64;
  __shared__ float hs[512];
  for (int i = threadIdx.x; i < 512; i += 128) hs[i] = h[(i >> 6) * 2048 + k0 + (i & 63)];
  __syncthreads();
  float acc[8] = {};
  for (int kk = 0; kk < 64; ++kk) {
    float w = W2[(size_t)(k0 + kk) * 128 + d];
#pragma unroll
    for (int b = 0; b < 8; ++b) acc[b] += hs[b * 64 + kk] * w;
  }
#pragma unroll
  for (int b = 0; b < 8; ++b) part2[((size_t)blockIdx.x * 8 + b) * 128 + d] = acc[b];
}

// per-batch: sum 32 partials + bias for q and k, l2-normalize, l_pos; grid 8, block 64
__global__ void k_head_fin(const float* __restrict__ p2q, const float* __restrict__ p2k,
                           const float* __restrict__ bq, const float* __restrict__ bk,
                           float* __restrict__ qg, float* __restrict__ kg,
                           float* __restrict__ lpos) {
  int b = blockIdx.x, lane = threadIdx.x;
  float q0 = bq[lane], q1 = bq[lane + 64];
  float k0 = bk[lane], k1 = bk[lane + 64];
#pragma unroll
  for (int s = 0; s < 32; ++s) {
    size_t base = ((size_t)s * 8 + b) * 128;
    q0 += p2q[base + lane]; q1 += p2q[base + lane + 64];
    k0 += p2k[base + lane]; k1 += p2k[base + lane + 64];
  }
  float sq = q0 * q0 + q1 * q1, sk = k0 * k0 + k1 * k1;
#pragma unroll
  for (int d = 1; d < 64; d <<= 1) { sq += __shfl_xor(sq, d); sk += __shfl_xor(sk, d); }
  float rq = 1.0f / sqrtf(fmaxf(sq, 1e-12f));
  float rk = 1.0f / sqrtf(fmaxf(sk, 1e-12f));
  q0 *= rq; q1 *= rq; k0 *= rk; k1 *= rk;
  qg[b * 128 + lane] = q0; qg[b * 128 + 64 + lane] = q1;
  kg[b * 128 + lane] = k0; kg[b * 128 + 64 + lane] = k1;
  float lp = q0 * k0 + q1 * k1;
#pragma unroll
  for (int d = 1; d < 64; d <<= 1) lp += __shfl_xor(lp, d);
  if (lane == 0) lpos[b] = lp;
}

// ---------------- transpose + convert: W[K,N] f32 -> Wt[N,K] bf16 ----------------
__global__ void k_transpose_cvt(const float* __restrict__ W, ushort* __restrict__ Wt, int K, int N) {
  __shared__ float tile[32][33];
  int n0 = blockIdx.x * 32, k0 = blockIdx.y * 32;
  int tx = threadIdx.x & 31, ty = threadIdx.x >> 5;
#pragma unroll
  for (int i = 0; i < 32; i += 8)
    tile[ty + i][tx] = W[(size_t)(k0 + ty + i) * N + n0 + tx];
  __syncthreads();
#pragma unroll
  for (int i = 0; i < 32; i += 8)
    Wt[(size_t)(n0 + ty + i) * K + k0 + tx] = f2bf(tile[tx][ty + i]);
}

// ---------------- MFMA GEMM: C = A[M,*lda] @ B[N,*ldb]^T over Kloop, bf16 in / f32 acc ----
// Staging: global_load_lds width=16, linear LDS dest, inverse-XOR-swizzled global source.
// EPI 0: +bias, relu, store bf16    EPI 2: per-row online (max,sumexp)*scale partials
// EPI 3: per-row (max,argmax)       EPI 4: store raw f32 at slice offset bz*ntiles
template <int EPI>
__global__ __launch_bounds__(256) void k_gemm_abt(
    const ushort* __restrict__ A, const ushort* __restrict__ B,
    const float* __restrict__ bias, void* __restrict__ o0, void* __restrict__ o1,
    int Mvalid, int Nvalid, int Kloop, int lda, int ldb, int ldOut, int ntiles,
    float scale, long sA, long sB) {
  __shared__ unsigned char smem[32768];
  unsigned char* As = smem;
  unsigned char* Bs = smem + 16384;
  const int tid = threadIdx.x;
  const int bx = blockIdx.x, by = blockIdx.y, bz = blockIdx.z;
  const ushort* Ab = A + (size_t)bz * sA;
  const ushort* Bb = B + (size_t)bz * sB;
  const int mBase = by * 128, nBase = bx * 128;
  const int lane = tid & 63;
  const int wid = tid >> 6;
  const int wm = wid >> 1, wn = wid & 1;
  const int lg = lane >> 4, li = lane & 15;
  // staging: wave stages rows [wid*32, wid*32+32) of each tile; gload_lds writes
  // lane l's 16B at ldsbase + l*16 (8 rows x 8 chunks). Source carries the XOR
  // swizzle so LDS chunk c at row r holds global chunk c^(r&7).
  const int sr0 = wid * 32 + (lane >> 3);
  f32x4 acc[4][4] = {};

  for (int k0 = 0; k0 < Kloop; k0 += 64) {
    __syncthreads();
#pragma unroll
    for (int j = 0; j < 4; ++j) {
      int r = sr0 + j * 8;
      int gc = (((lane & 7) ^ (r & 7)) << 3);  // element offset of 16B chunk
      int ga = mBase + r; ga = ga < Mvalid ? ga : Mvalid - 1;
      int gb = nBase + r; gb = gb < Nvalid ? gb : Nvalid - 1;
      gload_lds16(Ab + (size_t)ga * lda + k0 + gc, As + (size_t)(wid * 32 + j * 8) * 128);
      gload_lds16(Bb + (size_t)gb * ldb + k0 + gc, Bs + (size_t)(wid * 32 + j * 8) * 128);
    }
    __syncthreads();
#pragma unroll
    for (int ks = 0; ks < 2; ++ks) {
      s16x8 af[4], bfr[4];
#pragma unroll
      for (int mi = 0; mi < 4; ++mi) {
        int r = wm * 64 + mi * 16 + li;
        af[mi] = *(const s16x8*)(const void*)(As + r * 128 + ((ks * 64 + lg * 16) ^ ((r & 7) << 4)));
      }
#pragma unroll
      for (int ni = 0; ni < 4; ++ni) {
        int c = wn * 64 + ni * 16 + li;
        bfr[ni] = *(const s16x8*)(const void*)(Bs + c * 128 + ((ks * 64 + lg * 16) ^ ((c & 7) << 4)));
      }
#pragma unroll
      for (int mi = 0; mi < 4; ++mi)
#pragma unroll
        for (int ni = 0; ni < 4; ++ni)
          acc[mi][ni] = __builtin_amdgcn_mfma_f32_16x16x32_bf16(af[mi], bfr[ni], acc[mi][ni], 0, 0, 0);
    }
  }

  if constexpr (EPI == 0 || EPI == 4) {
#pragma unroll
    for (int mi = 0; mi < 4; ++mi)
#pragma unroll
      for (int ni = 0; ni < 4; ++ni) {
        int c = nBase + wn * 64 + ni * 16 + li;
#pragma unroll
        for (int rg = 0; rg < 4; ++rg) {
          int r = mBase + wm * 64 + mi * 16 + lg * 4 + rg;
          if (r < Mvalid && c < Nvalid) {
            if constexpr (EPI == 0) {
              float v = fmaxf(acc[mi][ni][rg] + bias[c], 0.f);
              ((ushort*)o0)[(size_t)r * ldOut + c] = f2bf(v);
            } else {
              ((float*)o0)[(size_t)bz * ntiles + (size_t)r * ldOut + c] = acc[mi][ni][rg];
            }
          }
        }
      }
  } else if constexpr (EPI == 2) {
    __syncthreads();
    float* redm = (float*)(void*)smem;   // [128][2]
    float* reds = redm + 256;
#pragma unroll
    for (int mi = 0; mi < 4; ++mi)
#pragma unroll
      for (int rg = 0; rg < 4; ++rg) {
        float v0 = acc[mi][0][rg] * scale;
        float v1 = acc[mi][1][rg] * scale;
        float v2 = acc[mi][2][rg] * scale;
        float v3 = acc[mi][3][rg] * scale;
        float m = fmaxf(fmaxf(v0, v1), fmaxf(v2, v3));
        float s = expf(v0 - m) + expf(v1 - m) + expf(v2 - m) + expf(v3 - m);
#pragma unroll
        for (int d = 1; d < 16; d <<= 1) {
          float om = __shfl_xor(m, d);
          float os = __shfl_xor(s, d);
          float nm = fmaxf(m, om);
          s = s * expf(m - nm) + os * expf(om - nm);
          m = nm;
        }
        int rl = wm * 64 + mi * 16 + lg * 4 + rg;
        if (li == 0) { redm[rl * 2 + wn] = m; reds[rl * 2 + wn] = s; }
      }
    __syncthreads();
    if (tid < 128) {
      float m0 = redm[tid * 2], m1 = redm[tid * 2 + 1];
      float s0 = reds[tid * 2], s1 = reds[tid * 2 + 1];
      float m = fmaxf(m0, m1);
      float s = s0 * expf(m0 - m) + s1 * expf(m1 - m);
      size_t idx = (size_t)(mBase + tid) * ntiles + bx;
      ((float*)o0)[idx] = m;
      ((float*)o1)[idx] = s;
    }
  } else if constexpr (EPI == 3) {
    __syncthreads();
    float* redv = (float*)(void*)smem;          // [128][2]
    int* redi = (int*)(void*)(smem + 1024);
#pragma unroll
    for (int mi = 0; mi < 4; ++mi)
#pragma unroll
      for (int rg = 0; rg < 4; ++rg) {
        float bv = -3.4e38f;
        int bi = 0x7fffffff;
#pragma unroll
        for (int ni = 0; ni < 4; ++ni) {
          int c = nBase + wn * 64 + ni * 16 + li;
          float v = (c < Nvalid) ? acc[mi][ni][rg] : -3.4e38f;
          if (v > bv || (v == bv && c < bi)) { bv = v; bi = c; }
        }
#pragma unroll
        for (int d = 1; d < 16; d <<= 1) {
          float ov = __shfl_xor(bv, d);
          int oi = __shfl_xor(bi, d);
          if (ov > bv || (ov == bv && oi < bi)) { bv = ov; bi = oi; }
        }
        int rl = wm * 64 + mi * 16 + lg * 4 + rg;
        if (li == 0) { redv[rl * 2 + wn] = bv; redi[rl * 2 + wn] = bi; }
      }
    __syncthreads();
    if (tid < 128) {
      int r = mBase + tid;
      if (r < Mvalid) {
        float v0 = redv[tid * 2], v1 = redv[tid * 2 + 1];
        int i0 = redi[tid * 2], i1 = redi[tid * 2 + 1];
        float v = v0; int bi2 = i0;
        if (v1 > v || (v1 == v && i1 < bi2)) { v = v1; bi2 = i1; }
        size_t idx = (size_t)(bz * Mvalid + r) * ntiles + bx;
        ((float*)o0)[idx] = v;
        ((int*)o1)[idx] = bi2;
      }
    }
  }
}

// ---------------- sum 4 K-slice partials + bias, l2-normalize, write f32 + bf16 --------
__global__ void k_l2n_rows(const float* __restrict__ part, const float* __restrict__ bias,
                           float* __restrict__ of, ushort* __restrict__ ob, int rows) {
  int row = blockIdx.x * 4 + (threadIdx.x >> 6);
  int lane = threadIdx.x & 63;
  if (row >= rows) return;
  size_t i0 = (size_t)row * 128 + lane;
  const size_t SL = 802816;  // 6272*128
  float v0 = bias[lane]      + part[i0]      + part[SL + i0]      + part[2 * SL + i0]      + part[3 * SL + i0];
  float v1 = bias[lane + 64] + part[i0 + 64] + part[SL + i0 + 64] + part[2 * SL + i0 + 64] + part[3 * SL + i0 + 64];
  float ss = v0 * v0 + v1 * v1;
#pragma unroll
  for (int d = 1; d < 64; d <<= 1) ss += __shfl_xor(ss, d);
  float r = 1.0f / sqrtf(fmaxf(ss, 1e-12f));
  of[i0] = v0 * r;
  of[i0 + 64] = v1 * r;
  ob[i0] = f2bf(v0 * r);
  ob[i0 + 64] = f2bf(v1 * r);
}

// ---------------- argmax finalize over 7 col-tiles + gather matched row ----------------
__global__ void k_argmax_gather(const float* __restrict__ pval, const int* __restrict__ pidx,
                                const ushort* __restrict__ kd_bf, ushort* __restrict__ matched_bf,
                                int* __restrict__ idxf) {
  int n = blockIdx.x;
  int b = n / 784;
  float bv = pval[(size_t)n * 7];
  int bi = pidx[(size_t)n * 7];
#pragma unroll
  for (int t = 1; t < 7; ++t) {
    float v = pval[(size_t)n * 7 + t];
    int i2 = pidx[(size_t)n * 7 + t];
    if (v > bv) { bv = v; bi = i2; }
  }
  int lane = threadIdx.x;
  if (lane == 0) idxf[n] = bi;
  const ushort* src = kd_bf + (size_t)(b * 784 + bi) * 128;
  ushort* dst = matched_bf + (size_t)n * 128;
  dst[lane] = src[lane];
  dst[lane + 64] = src[lane + 64];
}

// ---------------- queue InfoNCE partials ----------------
__global__ __launch_bounds__(256) void k_queue_nce(const float* __restrict__ queue,
                                                   const float* __restrict__ qg,
                                                   float* __restrict__ pm, float* __restrict__ ps) {
  __shared__ float qs[1024];
  int tid = threadIdx.x;
  for (int i = tid; i < 1024; i += 256) qs[i] = qg[i];
  __syncthreads();
  int r = blockIdx.x * 256 + tid;
  const float* qr = queue + (size_t)r * 128;
  float a[8] = {0, 0, 0, 0, 0, 0, 0, 0};
  for (int j = 0; j < 128; j += 4) {
    float4 v = *(const float4*)(const void*)(qr + j);
#pragma unroll
    for (int b = 0; b < 8; ++b)
      a[b] += v.x * qs[b * 128 + j] + v.y * qs[b * 128 + j + 1] +
              v.z * qs[b * 128 + j + 2] + v.w * qs[b * 128 + j + 3];
  }
  __shared__ float lm[8][4], lssum[8][4];
  int lane = tid & 63, w = tid >> 6;
#pragma unroll
  for (int b = 0; b < 8; ++b) {
    float m = a[b] * TAU_INV;
    float s = 1.0f;
#pragma unroll
    for (int d = 1; d < 64; d <<= 1) {
      float om = __shfl_xor(m, d), os = __shfl_xor(s, d);
      float nm = fmaxf(m, om);
      s = s * expf(m - nm) + os * expf(om - nm);
      m = nm;
    }
    if (lane == 0) { lm[b][w] = m; lssum[b][w] = s; }
  }
  __syncthreads();
  if (tid < 8) {
    int b = tid;
    float m = lm[b][0], s = lssum[b][0];
#pragma unroll
    for (int i = 1; i < 4; ++i) {
      float nm = fmaxf(m, lm[b][i]);
      s = s * expf(m - nm) + lssum[b][i] * expf(lm[b][i] - nm);
      m = nm;
    }
    pm[blockIdx.x * 8 + b] = m;
    ps[blockIdx.x * 8 + b] = s;
  }
}

// ---------------- per-row LSE combine + pos dot, wave per row; grid 1568 x 256 ---------
__global__ void k_row_lse(const float* __restrict__ pmax, const float* __restrict__ psum,
                          const int* __restrict__ idxf, const float* __restrict__ qd,
                          const float* __restrict__ kd, float* __restrict__ diff) {
  int n = blockIdx.x * 4 + (threadIdx.x >> 6);
  int lane = threadIdx.x & 63;
  float m = -3.4e38f, s = 0.f;
  if (lane < 49) {
    m = pmax[(size_t)n * 49 + lane];
    s = psum[(size_t)n * 49 + lane];
  }
#pragma unroll
  for (int d = 1; d < 64; d <<= 1) {
    float om = __shfl_xor(m, d), os = __shfl_xor(s, d);
    float nm = fmaxf(m, om);
    s = s * expf(m - nm) + os * expf(om - nm);
    m = nm;
  }
  int b = n / 784;
  int mr = b * 784 + idxf[n];
  float pos = qd[(size_t)n * 128 + lane] * kd[(size_t)mr * 128 + lane] +
              qd[(size_t)n * 128 + 64 + lane] * kd[(size_t)mr * 128 + 64 + lane];
#pragma unroll
  for (int d = 1; d < 64; d <<= 1) pos += __shfl_xor(pos, d);
  if (lane == 0) diff[n] = (m + logf(s)) - pos * TAU_INV;
}

// ---------------- final combine ----------------
__global__ void k_final(const float* __restrict__ pm, const float* __restrict__ ps,
                        const float* __restrict__ lpos, const float* __restrict__ diff,
                        float* __restrict__ out) {
  int tid = threadIdx.x;
  int lane = tid & 63, w = tid >> 6;
  __shared__ float sm[4], ssh[4];
  float lg = 0.f;
  for (int b = 0; b < 8; ++b) {
    float m = pm[tid * 8 + b], s = ps[tid * 8 + b];
#pragma unroll
    for (int d = 1; d < 64; d <<= 1) {
      float om = __shfl_xor(m, d), os = __shfl_xor(s, d);
      float nm = fmaxf(m, om);
      s = s * expf(m - nm) + os * expf(om - nm);
      m = nm;
    }
    if (lane == 0) { sm[w] = m; ssh[w] = s; }
    __syncthreads();
    if (tid == 0) {
      float M = sm[0], S = ssh[0];
      for (int i = 1; i < 4; ++i) {
        float nm = fmaxf(M, sm[i]);
        S = S * expf(M - nm) + ssh[i] * expf(sm[i] - nm);
        M = nm;
      }
      float lp = lpos[b] * TAU_INV;
      float nm = fmaxf(M, lp);
      S = S * expf(M - nm) + expf(lp - nm);
      M = nm;
      lg += (M + logf(S)) - lp;
    }
    __syncthreads();
  }
  float v = 0.f;
  for (int i = tid; i < 6272; i += 256) v += diff[i];
#pragma unroll
  for (int d = 1; d < 64; d <<= 1) v += __shfl_xor(v, d);
  if (lane == 0) sm[w] = v;
  __syncthreads();
  if (tid == 0) {
    float ld = sm[0] + sm[1] + sm[2] + sm[3];
    out[0] = 0.5f * (lg * 0.125f) + 0.5f * (ld * (1.0f / 6272.0f));
  }
}

extern "C" void kernel_launch(void* const* d_in, const int* in_sizes, int n_in,
                              void* d_out, int out_size, void* d_ws, size_t ws_size,
                              hipStream_t stream) {
  (void)in_sizes; (void)n_in; (void)out_size; (void)ws_size;
  const float* feat_q = (const float*)d_in[0];
  const float* feat_k = (const float*)d_in[1];
  const float* Wg1 = (const float*)d_in[2];
  const float* bg1 = (const float*)d_in[3];
  const float* Wg2 = (const float*)d_in[4];
  const float* bg2 = (const float*)d_in[5];
  const float* Wd1 = (const float*)d_in[6];
  const float* bd1 = (const float*)d_in[7];
  const float* Wd2 = (const float*)d_in[8];
  const float* bd2 = (const float*)d_in[9];
  const float* mWg1 = (const float*)d_in[10];
  const float* mbg1 = (const float*)d_in[11];
  const float* mWg2 = (const float*)d_in[12];
  const float* mbg2 = (const float*)d_in[13];
  const float* mWd1 = (const float*)d_in[14];
  const float* mbd1 = (const float*)d_in[15];
  const float* mWd2 = (const float*)d_in[16];
  const float* mbd2 = (const float*)d_in[17];
  const float* queue = (const float*)d_in[18];
  float* out = (float*)d_out;

  char* ws = (char*)d_ws;
  size_t off = 0;
  auto alloc = [&](size_t bytes) -> void* {
    void* p = (void*)(ws + off);
    off += (bytes + 255) & ~(size_t)255;
    return p;
  };

  ushort* featq_bf = (ushort*)alloc(6272ull * 1024 * 2);
  ushort* featk_bf = (ushort*)alloc(6272ull * 1024 * 2);
  ushort* Wd1t = (ushort*)alloc(2048ull * 1024 * 2);
  ushort* mWd1t = (ushort*)alloc(2048ull * 1024 * 2);
  ushort* Wd2t = (ushort*)alloc(128ull * 2048 * 2);
  ushort* mWd2t = (ushort*)alloc(128ull * 2048 * 2);
  ushort* h_bf = (ushort*)alloc(6272ull * 2048 * 2);
  float* e2part = (float*)alloc(4ull * 6272 * 128 * 4);
  float* qd = (float*)alloc(6272ull * 128 * 4);
  float* kd = (float*)alloc(6272ull * 128 * 4);
  ushort* qd_bf = (ushort*)alloc(6272ull * 128 * 2);
  ushort* kd_bf = (ushort*)alloc(6272ull * 128 * 2);
  ushort* matched_bf = (ushort*)alloc(6272ull * 128 * 2);
  float* pmax = (float*)alloc(6272ull * 49 * 4);
  float* psum = (float*)alloc(6272ull * 49 * 4);
  float* pval = (float*)alloc(6272ull * 7 * 4);
  int* pidx = (int*)alloc(6272ull * 7 * 4);
  int* idxf = (int*)alloc(6272ull * 4);
  float* gpart = (float*)alloc(8ull * 112 * 1024 * 4);
  float* gq = (float*)alloc(8ull * 1024 * 4);
  float* gk = (float*)alloc(8ull * 1024 * 4);
  float* part1 = (float*)alloc(16ull * 8 * 2048 * 4);
  float* hgq = (float*)alloc(8ull * 2048 * 4);
  float* hgk = (float*)alloc(8ull * 2048 * 4);
  float* part2q = (float*)alloc(32ull * 8 * 128 * 4);
  float* part2k = (float*)alloc(32ull * 8 * 128 * 4);
  float* qg = (float*)alloc(8ull * 128 * 4);
  float* kg = (float*)alloc(8ull * 128 * 4);
  float* l_pos = (float*)alloc(8ull * 4);
  float* qpart_m = (float*)alloc(256ull * 8 * 4);
  float* qpart_s = (float*)alloc(256ull * 8 * 4);
  float* diff = (float*)alloc(6272ull * 4);

  // fused convert + pool partials (q then k; gpart reused sequentially)
  k_cvt_pool<<<dim3(112, 8), 256, 0, stream>>>(feat_q, featq_bf, gpart);
  k_gpool_fin<<<32, 256, 0, stream>>>(gpart, gq);
  k_cvt_pool<<<dim3(112, 8), 256, 0, stream>>>(feat_k, featk_bf, gpart);
  k_gpool_fin<<<32, 256, 0, stream>>>(gpart, gk);

  // weight transposes
  k_transpose_cvt<<<dim3(64, 32), 256, 0, stream>>>(Wd1, Wd1t, 1024, 2048);
  k_transpose_cvt<<<dim3(64, 32), 256, 0, stream>>>(mWd1, mWd1t, 1024, 2048);
  k_transpose_cvt<<<dim3(4, 64), 256, 0, stream>>>(Wd2, Wd2t, 2048, 128);
  k_transpose_cvt<<<dim3(4, 64), 256, 0, stream>>>(mWd2, mWd2t, 2048, 128);

  // global head, student then momentum (part1/hg buffers sequential)
  k_dense1_part<<<dim3(8, 16), 256, 0, stream>>>(gq, Wg1, part1);
  k_dense1_fin<<<64, 256, 0, stream>>>(part1, bg1, hgq);
  k_dense2_part<<<32, 128, 0, stream>>>(hgq, Wg2, part2q);
  k_dense1_part<<<dim3(8, 16), 256, 0, stream>>>(gk, mWg1, part1);
  k_dense1_fin<<<64, 256, 0, stream>>>(part1, mbg1, hgk);
  k_dense2_part<<<32, 128, 0, stream>>>(hgk, mWg2, part2k);
  k_head_fin<<<8, 64, 0, stream>>>(part2q, part2k, bg2, mbg2, qg, kg, l_pos);

  // dense head, student
  k_gemm_abt<0><<<dim3(16, 49, 1), 256, 0, stream>>>(featq_bf, Wd1t, bd1, h_bf, nullptr,
                                                     6272, 2048, 1024, 1024, 1024, 2048, 0, 0.f, 0, 0);
  k_gemm_abt<4><<<dim3(1, 49, 4), 256, 0, stream>>>(h_bf, Wd2t, nullptr, e2part, nullptr,
                                                    6272, 128, 512, 2048, 2048, 128, 802816, 0.f, 512, 512);
  k_l2n_rows<<<1568, 256, 0, stream>>>(e2part, bd2, qd, qd_bf, 6272);

  // dense head, momentum
  k_gemm_abt<0><<<dim3(16, 49, 1), 256, 0, stream>>>(featk_bf, mWd1t, mbd1, h_bf, nullptr,
                                                     6272, 2048, 1024, 1024, 1024, 2048, 0, 0.f, 0, 0);
  k_gemm_abt<4><<<dim3(1, 49, 4), 256, 0, stream>>>(h_bf, mWd2t, nullptr, e2part, nullptr,
                                                    6272, 128, 512, 2048, 2048, 128, 802816, 0.f, 512, 512);
  k_l2n_rows<<<1568, 256, 0, stream>>>(e2part, mbd2, kd, kd_bf, 6272);

  // dense correspondence (batched argmax)
  k_gemm_abt<3><<<dim3(7, 7, 8), 256, 0, stream>>>(qd_bf, kd_bf, nullptr, pval, pidx,
                                                   784, 784, 128, 128, 128, 0, 7, 0.f,
                                                   784l * 128, 784l * 128);
  k_argmax_gather<<<6272, 64, 0, stream>>>(pval, pidx, kd_bf, matched_bf, idxf);

  // dense InfoNCE lse partials (6272 x 6272)
  k_gemm_abt<2><<<dim3(49, 49, 1), 256, 0, stream>>>(qd_bf, matched_bf, nullptr, pmax, psum,
                                                     6272, 6272, 128, 128, 128, 0, 49, TAU_INV, 0, 0);

  // queue InfoNCE
  k_queue_nce<<<256, 256, 0, stream>>>(queue, qg, qpart_m, qpart_s);

  // finalize losses
  k_row_lse<<<1568, 256, 0, stream>>>(pmax, psum, idxf, qd, kd, diff);
  k_final<<<1, 256, 0, stream>>>(qpart_m, qpart_s, l_pos, diff, out);
}

// Round 4
// 340.779 us; speedup vs baseline: 2.3385x; 1.1020x over previous
//
#include <hip/hip_runtime.h>
#include <cstdint>

#define TAU_INV 5.0f
#define L2E 1.4426950408889634f

using ushort = unsigned short;
typedef __attribute__((ext_vector_type(8))) short s16x8;
typedef __attribute__((ext_vector_type(4))) float f32x4;

static __device__ __forceinline__ ushort f2bf(float x) {
  unsigned u = __float_as_uint(x);
  return (ushort)((u + 0x7fffu + ((u >> 16) & 1u)) >> 16);
}

static __device__ __forceinline__ float fexp2(float x) {
#if __has_builtin(__builtin_amdgcn_exp2f)
  return __builtin_amdgcn_exp2f(x);
#else
  return exp2f(x);
#endif
}
// exp(a-b) with natural-log semantics, via v_exp_f32
static __device__ __forceinline__ float fexpd(float a, float b) {
  return fexp2((a - b) * L2E);
}

static __device__ __forceinline__ void gload_lds16(const void* g, void* l) {
  __builtin_amdgcn_global_load_lds(
      reinterpret_cast<const __attribute__((address_space(1))) void*>(
          reinterpret_cast<uintptr_t>(g)),
      reinterpret_cast<__attribute__((address_space(3))) void*>(
          (unsigned)reinterpret_cast<uintptr_t>(l)),
      16, 0, 0);
}

// ---------------- fused f32->bf16 convert + partial channel pool ----------------
__global__ void k_cvt_pool(const float* __restrict__ feat, ushort* __restrict__ obf,
                           float* __restrict__ gpart) {
  int b = blockIdx.y, pc = blockIdx.x, t = threadIdx.x;
  const float* fp = feat + ((size_t)b * 784 + (size_t)pc * 7) * 1024;
  ushort* op = obf + ((size_t)b * 784 + (size_t)pc * 7) * 1024;
  float4 acc = {0.f, 0.f, 0.f, 0.f};
#pragma unroll
  for (int p = 0; p < 7; ++p) {
    float4 v = ((const float4*)(fp + (size_t)p * 1024))[t];
    acc.x += v.x; acc.y += v.y; acc.z += v.z; acc.w += v.w;
    ushort4 r;
    r.x = f2bf(v.x); r.y = f2bf(v.y); r.z = f2bf(v.z); r.w = f2bf(v.w);
    ((ushort4*)(op + (size_t)p * 1024))[t] = r;
  }
  ((float4*)(gpart + ((size_t)b * 112 + pc) * 1024))[t] = acc;
}

__global__ void k_gpool_fin(const float* __restrict__ gpart, float* __restrict__ g) {
  int idx = blockIdx.x * 256 + threadIdx.x;
  int b = idx >> 10, c = idx & 1023;
  float s = 0.f;
#pragma unroll 4
  for (int pc = 0; pc < 112; ++pc) s += gpart[((size_t)b * 112 + pc) * 1024 + c];
  g[idx] = s * (1.0f / 784.0f);
}

__global__ void k_dense1_part(const float* __restrict__ g, const float* __restrict__ W,
                              float* __restrict__ part1) {
  int d = blockIdx.x * 256 + threadIdx.x;
  int k0 = blockIdx.y * 64;
  __shared__ float gs[512];
  for (int i = threadIdx.x; i < 512; i += 256) gs[i] = g[(i >> 6) * 1024 + k0 + (i & 63)];
  __syncthreads();
  float acc[8] = {};
  for (int kk = 0; kk < 64; ++kk) {
    float w = W[(size_t)(k0 + kk) * 2048 + d];
#pragma unroll
    for (int b = 0; b < 8; ++b) acc[b] += gs[b * 64 + kk] * w;
  }
#pragma unroll
  for (int b = 0; b < 8; ++b) part1[((size_t)blockIdx.y * 8 + b) * 2048 + d] = acc[b];
}

__global__ void k_dense1_fin(const float* __restrict__ part1, const float* __restrict__ bias,
                             float* __restrict__ h) {
  int idx = blockIdx.x * 256 + threadIdx.x;
  int b = idx >> 11, d = idx & 2047;
  float s = bias[d];
#pragma unroll
  for (int ks = 0; ks < 16; ++ks) s += part1[((size_t)ks * 8 + b) * 2048 + d];
  h[idx] = fmaxf(s, 0.f);
}

__global__ void k_dense2_part(const float* __restrict__ h, const float* __restrict__ W2,
                              float* __restrict__ part2) {
  int d = threadIdx.x;
  int k0 = blockIdx.x * 64;
  __shared__ float hs[512];
  for (int i = threadIdx.x; i < 512; i += 128) hs[i] = h[(i >> 6) * 2048 + k0 + (i & 63)];
  __syncthreads();
  float acc[8] = {};
  for (int kk = 0; kk < 64; ++kk) {
    float w = W2[(size_t)(k0 + kk) * 128 + d];
#pragma unroll
    for (int b = 0; b < 8; ++b) acc[b] += hs[b * 64 + kk] * w;
  }
#pragma unroll
  for (int b = 0; b < 8; ++b) part2[((size_t)blockIdx.x * 8 + b) * 128 + d] = acc[b];
}

__global__ void k_head_fin(const float* __restrict__ p2q, const float* __restrict__ p2k,
                           const float* __restrict__ bq, const float* __restrict__ bk,
                           float* __restrict__ qg, float* __restrict__ kg,
                           float* __restrict__ lpos) {
  int b = blockIdx.x, lane = threadIdx.x;
  float q0 = bq[lane], q1 = bq[lane + 64];
  float k0 = bk[lane], k1 = bk[lane + 64];
#pragma unroll
  for (int s = 0; s < 32; ++s) {
    size_t base = ((size_t)s * 8 + b) * 128;
    q0 += p2q[base + lane]; q1 += p2q[base + lane + 64];
    k0 += p2k[base + lane]; k1 += p2k[base + lane + 64];
  }
  float sq = q0 * q0 + q1 * q1, sk = k0 * k0 + k1 * k1;
#pragma unroll
  for (int d = 1; d < 64; d <<= 1) { sq += __shfl_xor(sq, d); sk += __shfl_xor(sk, d); }
  float rq = 1.0f / sqrtf(fmaxf(sq, 1e-12f));
  float rk = 1.0f / sqrtf(fmaxf(sk, 1e-12f));
  q0 *= rq; q1 *= rq; k0 *= rk; k1 *= rk;
  qg[b * 128 + lane] = q0; qg[b * 128 + 64 + lane] = q1;
  kg[b * 128 + lane] = k0; kg[b * 128 + 64 + lane] = k1;
  float lp = q0 * k0 + q1 * k1;
#pragma unroll
  for (int d = 1; d < 64; d <<= 1) lp += __shfl_xor(lp, d);
  if (lane == 0) lpos[b] = lp;
}

// ---------------- transpose + convert ----------------
__global__ void k_transpose_cvt(const float* __restrict__ W, ushort* __restrict__ Wt, int K, int N) {
  __shared__ float tile[32][33];
  int n0 = blockIdx.x * 32, k0 = blockIdx.y * 32;
  int tx = threadIdx.x & 31, ty = threadIdx.x >> 5;
#pragma unroll
  for (int i = 0; i < 32; i += 8)
    tile[ty + i][tx] = W[(size_t)(k0 + ty + i) * N + n0 + tx];
  __syncthreads();
#pragma unroll
  for (int i = 0; i < 32; i += 8)
    Wt[(size_t)(n0 + ty + i) * K + k0 + tx] = f2bf(tile[tx][ty + i]);
}

// ---------------- MFMA GEMM ----------------
template <int EPI>
__global__ __launch_bounds__(256) void k_gemm_abt(
    const ushort* __restrict__ A, const ushort* __restrict__ B,
    const float* __restrict__ bias, void* __restrict__ o0, void* __restrict__ o1,
    int Mvalid, int Nvalid, int Kloop, int lda, int ldb, int ldOut, int ntiles,
    float scale, long sA, long sB) {
  __shared__ unsigned char smem[32768];
  unsigned char* As = smem;
  unsigned char* Bs = smem + 16384;
  const int tid = threadIdx.x;
  const int bx = blockIdx.x, by = blockIdx.y, bz = blockIdx.z;
  const ushort* Ab = A + (size_t)bz * sA;
  const ushort* Bb = B + (size_t)bz * sB;
  const int mBase = by * 128, nBase = bx * 128;
  const int lane = tid & 63;
  const int wid = tid >> 6;
  const int wid_u = __builtin_amdgcn_readfirstlane(wid);   // provably wave-uniform
  const int wm = wid >> 1, wn = wid & 1;
  const int lg = lane >> 4, li = lane & 15;
  const int lrow = lane >> 3, lchunk = lane & 7;

  // hoisted staging addresses (loop-invariant over k0)
  const ushort* aSrc[4];
  const ushort* bSrc[4];
  int ldsOff[4];
#pragma unroll
  for (int j = 0; j < 4; ++j) {
    int r = wid_u * 32 + j * 8 + lrow;
    int gc = (lchunk ^ lrow) << 3;   // (r&7)==lrow
    int ga = mBase + r; ga = ga < Mvalid ? ga : Mvalid - 1;
    int gb = nBase + r; gb = gb < Nvalid ? gb : Nvalid - 1;
    aSrc[j] = Ab + (size_t)ga * lda + gc;
    bSrc[j] = Bb + (size_t)gb * ldb + gc;
    ldsOff[j] = (wid_u * 32 + j * 8) * 128;
  }
  f32x4 acc[4][4] = {};

  for (int k0 = 0; k0 < Kloop; k0 += 64) {
    __syncthreads();
#pragma unroll
    for (int j = 0; j < 4; ++j) {
      gload_lds16(aSrc[j] + k0, As + ldsOff[j]);
      gload_lds16(bSrc[j] + k0, Bs + ldsOff[j]);
    }
    __syncthreads();
#pragma unroll
    for (int ks = 0; ks < 2; ++ks) {
      s16x8 af[4], bfr[4];
#pragma unroll
      for (int mi = 0; mi < 4; ++mi) {
        int r = wm * 64 + mi * 16 + li;
        af[mi] = *(const s16x8*)(const void*)(As + r * 128 + ((ks * 64 + lg * 16) ^ ((r & 7) << 4)));
      }
#pragma unroll
      for (int ni = 0; ni < 4; ++ni) {
        int c = wn * 64 + ni * 16 + li;
        bfr[ni] = *(const s16x8*)(const void*)(Bs + c * 128 + ((ks * 64 + lg * 16) ^ ((c & 7) << 4)));
      }
#pragma unroll
      for (int mi = 0; mi < 4; ++mi)
#pragma unroll
        for (int ni = 0; ni < 4; ++ni)
          acc[mi][ni] = __builtin_amdgcn_mfma_f32_16x16x32_bf16(af[mi], bfr[ni], acc[mi][ni], 0, 0, 0);
    }
  }

  if constexpr (EPI == 0 || EPI == 4) {
#pragma unroll
    for (int mi = 0; mi < 4; ++mi)
#pragma unroll
      for (int ni = 0; ni < 4; ++ni) {
        int c = nBase + wn * 64 + ni * 16 + li;
#pragma unroll
        for (int rg = 0; rg < 4; ++rg) {
          int r = mBase + wm * 64 + mi * 16 + lg * 4 + rg;
          if (r < Mvalid && c < Nvalid) {
            if constexpr (EPI == 0) {
              float v = fmaxf(acc[mi][ni][rg] + bias[c], 0.f);
              ((ushort*)o0)[(size_t)r * ldOut + c] = f2bf(v);
            } else {
              ((float*)o0)[(size_t)bz * ntiles + (size_t)r * ldOut + c] = acc[mi][ni][rg];
            }
          }
        }
      }
  } else if constexpr (EPI == 2) {
    __syncthreads();
    float* redm = (float*)(void*)smem;   // [128][2]
    float* reds = redm + 256;
#pragma unroll
    for (int mi = 0; mi < 4; ++mi)
#pragma unroll
      for (int rg = 0; rg < 4; ++rg) {
        float v0 = acc[mi][0][rg] * scale;
        float v1 = acc[mi][1][rg] * scale;
        float v2 = acc[mi][2][rg] * scale;
        float v3 = acc[mi][3][rg] * scale;
        // max-first: fmax-only reduce, then exp-once, add-only reduce
        float m = fmaxf(fmaxf(v0, v1), fmaxf(v2, v3));
#pragma unroll
        for (int d = 1; d < 16; d <<= 1) m = fmaxf(m, __shfl_xor(m, d));
        float s = fexpd(v0, m) + fexpd(v1, m) + fexpd(v2, m) + fexpd(v3, m);
#pragma unroll
        for (int d = 1; d < 16; d <<= 1) s += __shfl_xor(s, d);
        int rl = wm * 64 + mi * 16 + lg * 4 + rg;
        if (li == 0) { redm[rl * 2 + wn] = m; reds[rl * 2 + wn] = s; }
      }
    __syncthreads();
    if (tid < 128) {
      float m0 = redm[tid * 2], m1 = redm[tid * 2 + 1];
      float s0 = reds[tid * 2], s1 = reds[tid * 2 + 1];
      float m = fmaxf(m0, m1);
      float s = s0 * fexpd(m0, m) + s1 * fexpd(m1, m);
      size_t idx = (size_t)(mBase + tid) * ntiles + bx;
      ((float*)o0)[idx] = m;
      ((float*)o1)[idx] = s;
    }
  } else if constexpr (EPI == 3) {
    __syncthreads();
    float* redv = (float*)(void*)smem;
    int* redi = (int*)(void*)(smem + 1024);
#pragma unroll
    for (int mi = 0; mi < 4; ++mi)
#pragma unroll
      for (int rg = 0; rg < 4; ++rg) {
        float bv = -3.4e38f;
        int bi = 0x7fffffff;
#pragma unroll
        for (int ni = 0; ni < 4; ++ni) {
          int c = nBase + wn * 64 + ni * 16 + li;
          float v = (c < Nvalid) ? acc[mi][ni][rg] : -3.4e38f;
          if (v > bv || (v == bv && c < bi)) { bv = v; bi = c; }
        }
#pragma unroll
        for (int d = 1; d < 16; d <<= 1) {
          float ov = __shfl_xor(bv, d);
          int oi = __shfl_xor(bi, d);
          if (ov > bv || (ov == bv && oi < bi)) { bv = ov; bi = oi; }
        }
        int rl = wm * 64 + mi * 16 + lg * 4 + rg;
        if (li == 0) { redv[rl * 2 + wn] = bv; redi[rl * 2 + wn] = bi; }
      }
    __syncthreads();
    if (tid < 128) {
      int r = mBase + tid;
      if (r < Mvalid) {
        float v0 = redv[tid * 2], v1 = redv[tid * 2 + 1];
        int i0 = redi[tid * 2], i1 = redi[tid * 2 + 1];
        float v = v0; int bi2 = i0;
        if (v1 > v || (v1 == v && i1 < bi2)) { v = v1; bi2 = i1; }
        size_t idx = (size_t)(bz * Mvalid + r) * ntiles + bx;
        ((float*)o0)[idx] = v;
        ((int*)o1)[idx] = bi2;
      }
    }
  }
}

// ---------------- sum 4 K-slice partials + bias, l2-normalize ----------------
__global__ void k_l2n_rows(const float* __restrict__ part, const float* __restrict__ bias,
                           float* __restrict__ of, ushort* __restrict__ ob, int rows) {
  int row = blockIdx.x * 4 + (threadIdx.x >> 6);
  int lane = threadIdx.x & 63;
  if (row >= rows) return;
  size_t i0 = (size_t)row * 128 + lane;
  const size_t SL = 802816;
  float v0 = bias[lane]      + part[i0]      + part[SL + i0]      + part[2 * SL + i0]      + part[3 * SL + i0];
  float v1 = bias[lane + 64] + part[i0 + 64] + part[SL + i0 + 64] + part[2 * SL + i0 + 64] + part[3 * SL + i0 + 64];
  float ss = v0 * v0 + v1 * v1;
#pragma unroll
  for (int d = 1; d < 64; d <<= 1) ss += __shfl_xor(ss, d);
  float r = 1.0f / sqrtf(fmaxf(ss, 1e-12f));
  of[i0] = v0 * r;
  of[i0 + 64] = v1 * r;
  ob[i0] = f2bf(v0 * r);
  ob[i0 + 64] = f2bf(v1 * r);
}

// ---------------- argmax finalize + gather ----------------
__global__ void k_argmax_gather(const float* __restrict__ pval, const int* __restrict__ pidx,
                                const ushort* __restrict__ kd_bf, ushort* __restrict__ matched_bf,
                                int* __restrict__ idxf) {
  int n = blockIdx.x;
  int b = n / 784;
  float bv = pval[(size_t)n * 7];
  int bi = pidx[(size_t)n * 7];
#pragma unroll
  for (int t = 1; t < 7; ++t) {
    float v = pval[(size_t)n * 7 + t];
    int i2 = pidx[(size_t)n * 7 + t];
    if (v > bv) { bv = v; bi = i2; }
  }
  int lane = threadIdx.x;
  if (lane == 0) idxf[n] = bi;
  const ushort* src = kd_bf + (size_t)(b * 784 + bi) * 128;
  ushort* dst = matched_bf + (size_t)n * 128;
  dst[lane] = src[lane];
  dst[lane + 64] = src[lane + 64];
}

// ---------------- queue InfoNCE partials (max-first) ----------------
__global__ __launch_bounds__(256) void k_queue_nce(const float* __restrict__ queue,
                                                   const float* __restrict__ qg,
                                                   float* __restrict__ pm, float* __restrict__ ps) {
  __shared__ float qs[1024];
  int tid = threadIdx.x;
  for (int i = tid; i < 1024; i += 256) qs[i] = qg[i];
  __syncthreads();
  int r = blockIdx.x * 256 + tid;
  const float* qr = queue + (size_t)r * 128;
  float a[8] = {0, 0, 0, 0, 0, 0, 0, 0};
  for (int j = 0; j < 128; j += 4) {
    float4 v = *(const float4*)(const void*)(qr + j);
#pragma unroll
    for (int b = 0; b < 8; ++b)
      a[b] += v.x * qs[b * 128 + j] + v.y * qs[b * 128 + j + 1] +
              v.z * qs[b * 128 + j + 2] + v.w * qs[b * 128 + j + 3];
  }
  __shared__ float lm[8][4], lssum[8][4];
  int lane = tid & 63, w = tid >> 6;
#pragma unroll
  for (int b = 0; b < 8; ++b) {
    float v = a[b] * TAU_INV;
    float m = v;
#pragma unroll
    for (int d = 1; d < 64; d <<= 1) m = fmaxf(m, __shfl_xor(m, d));
    float s = fexpd(v, m);
#pragma unroll
    for (int d = 1; d < 64; d <<= 1) s += __shfl_xor(s, d);
    if (lane == 0) { lm[b][w] = m; lssum[b][w] = s; }
  }
  __syncthreads();
  if (tid < 8) {
    int b = tid;
    float m = lm[b][0], s = lssum[b][0];
#pragma unroll
    for (int i = 1; i < 4; ++i) {
      float nm = fmaxf(m, lm[b][i]);
      s = s * fexpd(m, nm) + lssum[b][i] * fexpd(lm[b][i], nm);
      m = nm;
    }
    pm[blockIdx.x * 8 + b] = m;
    ps[blockIdx.x * 8 + b] = s;
  }
}

// ---------------- per-row LSE combine (max-first) + pos dot ----------------
__global__ void k_row_lse(const float* __restrict__ pmax, const float* __restrict__ psum,
                          const int* __restrict__ idxf, const float* __restrict__ qd,
                          const float* __restrict__ kd, float* __restrict__ diff) {
  int n = blockIdx.x * 4 + (threadIdx.x >> 6);
  int lane = threadIdx.x & 63;
  float m = -3.4e38f, s = 0.f;
  if (lane < 49) {
    m = pmax[(size_t)n * 49 + lane];
    s = psum[(size_t)n * 49 + lane];
  }
  float M = m;
#pragma unroll
  for (int d = 1; d < 64; d <<= 1) M = fmaxf(M, __shfl_xor(M, d));
  s *= fexpd(m, M);  // invalid lanes: exp2(-inf)=0
#pragma unroll
  for (int d = 1; d < 64; d <<= 1) s += __shfl_xor(s, d);
  int b = n / 784;
  int mr = b * 784 + idxf[n];
  float pos = qd[(size_t)n * 128 + lane] * kd[(size_t)mr * 128 + lane] +
              qd[(size_t)n * 128 + 64 + lane] * kd[(size_t)mr * 128 + 64 + lane];
#pragma unroll
  for (int d = 1; d < 64; d <<= 1) pos += __shfl_xor(pos, d);
  if (lane == 0) diff[n] = (M + logf(s)) - pos * TAU_INV;
}

// ---------------- final combine ----------------
__global__ void k_final(const float* __restrict__ pm, const float* __restrict__ ps,
                        const float* __restrict__ lpos, const float* __restrict__ diff,
                        float* __restrict__ out) {
  int tid = threadIdx.x;
  int lane = tid & 63, w = tid >> 6;
  __shared__ float sm[4], ssh[4];
  float lg = 0.f;
  for (int b = 0; b < 8; ++b) {
    float m = pm[tid * 8 + b], s = ps[tid * 8 + b];
    float M = m;
#pragma unroll
    for (int d = 1; d < 64; d <<= 1) M = fmaxf(M, __shfl_xor(M, d));
    s *= fexpd(m, M);
#pragma unroll
    for (int d = 1; d < 64; d <<= 1) s += __shfl_xor(s, d);
    if (lane == 0) { sm[w] = M; ssh[w] = s; }
    __syncthreads();
    if (tid == 0) {
      float M2 = sm[0], S = ssh[0];
      for (int i = 1; i < 4; ++i) {
        float nm = fmaxf(M2, sm[i]);
        S = S * fexpd(M2, nm) + ssh[i] * fexpd(sm[i], nm);
        M2 = nm;
      }
      float lp = lpos[b] * TAU_INV;
      float nm = fmaxf(M2, lp);
      S = S * fexpd(M2, nm) + fexpd(lp, nm);
      M2 = nm;
      lg += (M2 + logf(S)) - lp;
    }
    __syncthreads();
  }
  float v = 0.f;
  for (int i = tid; i < 6272; i += 256) v += diff[i];
#pragma unroll
  for (int d = 1; d < 64; d <<= 1) v += __shfl_xor(v, d);
  if (lane == 0) sm[w] = v;
  __syncthreads();
  if (tid == 0) {
    float ld = sm[0] + sm[1] + sm[2] + sm[3];
    out[0] = 0.5f * (lg * 0.125f) + 0.5f * (ld * (1.0f / 6272.0f));
  }
}

extern "C" void kernel_launch(void* const* d_in, const int* in_sizes, int n_in,
                              void* d_out, int out_size, void* d_ws, size_t ws_size,
                              hipStream_t stream) {
  (void)in_sizes; (void)n_in; (void)out_size; (void)ws_size;
  const float* feat_q = (const float*)d_in[0];
  const float* feat_k = (const float*)d_in[1];
  const float* Wg1 = (const float*)d_in[2];
  const float* bg1 = (const float*)d_in[3];
  const float* Wg2 = (const float*)d_in[4];
  const float* bg2 = (const float*)d_in[5];
  const float* Wd1 = (const float*)d_in[6];
  const float* bd1 = (const float*)d_in[7];
  const float* Wd2 = (const float*)d_in[8];
  const float* bd2 = (const float*)d_in[9];
  const float* mWg1 = (const float*)d_in[10];
  const float* mbg1 = (const float*)d_in[11];
  const float* mWg2 = (const float*)d_in[12];
  const float* mbg2 = (const float*)d_in[13];
  const float* mWd1 = (const float*)d_in[14];
  const float* mbd1 = (const float*)d_in[15];
  const float* mWd2 = (const float*)d_in[16];
  const float* mbd2 = (const float*)d_in[17];
  const float* queue = (const float*)d_in[18];
  float* out = (float*)d_out;

  char* ws = (char*)d_ws;
  size_t off = 0;
  auto alloc = [&](size_t bytes) -> void* {
    void* p = (void*)(ws + off);
    off += (bytes + 255) & ~(size_t)255;
    return p;
  };

  ushort* featq_bf = (ushort*)alloc(6272ull * 1024 * 2);
  ushort* featk_bf = (ushort*)alloc(6272ull * 1024 * 2);
  ushort* Wd1t = (ushort*)alloc(2048ull * 1024 * 2);
  ushort* mWd1t = (ushort*)alloc(2048ull * 1024 * 2);
  ushort* Wd2t = (ushort*)alloc(128ull * 2048 * 2);
  ushort* mWd2t = (ushort*)alloc(128ull * 2048 * 2);
  ushort* h_bf = (ushort*)alloc(6272ull * 2048 * 2);
  float* e2part = (float*)alloc(4ull * 6272 * 128 * 4);
  float* qd = (float*)alloc(6272ull * 128 * 4);
  float* kd = (float*)alloc(6272ull * 128 * 4);
  ushort* qd_bf = (ushort*)alloc(6272ull * 128 * 2);
  ushort* kd_bf = (ushort*)alloc(6272ull * 128 * 2);
  ushort* matched_bf = (ushort*)alloc(6272ull * 128 * 2);
  float* pmax = (float*)alloc(6272ull * 49 * 4);
  float* psum = (float*)alloc(6272ull * 49 * 4);
  float* pval = (float*)alloc(6272ull * 7 * 4);
  int* pidx = (int*)alloc(6272ull * 7 * 4);
  int* idxf = (int*)alloc(6272ull * 4);
  float* gpart = (float*)alloc(8ull * 112 * 1024 * 4);
  float* gq = (float*)alloc(8ull * 1024 * 4);
  float* gk = (float*)alloc(8ull * 1024 * 4);
  float* part1 = (float*)alloc(16ull * 8 * 2048 * 4);
  float* hgq = (float*)alloc(8ull * 2048 * 4);
  float* hgk = (float*)alloc(8ull * 2048 * 4);
  float* part2q = (float*)alloc(32ull * 8 * 128 * 4);
  float* part2k = (float*)alloc(32ull * 8 * 128 * 4);
  float* qg = (float*)alloc(8ull * 128 * 4);
  float* kg = (float*)alloc(8ull * 128 * 4);
  float* l_pos = (float*)alloc(8ull * 4);
  float* qpart_m = (float*)alloc(256ull * 8 * 4);
  float* qpart_s = (float*)alloc(256ull * 8 * 4);
  float* diff = (float*)alloc(6272ull * 4);

  k_cvt_pool<<<dim3(112, 8), 256, 0, stream>>>(feat_q, featq_bf, gpart);
  k_gpool_fin<<<32, 256, 0, stream>>>(gpart, gq);
  k_cvt_pool<<<dim3(112, 8), 256, 0, stream>>>(feat_k, featk_bf, gpart);
  k_gpool_fin<<<32, 256, 0, stream>>>(gpart, gk);

  k_transpose_cvt<<<dim3(64, 32), 256, 0, stream>>>(Wd1, Wd1t, 1024, 2048);
  k_transpose_cvt<<<dim3(64, 32), 256, 0, stream>>>(mWd1, mWd1t, 1024, 2048);
  k_transpose_cvt<<<dim3(4, 64), 256, 0, stream>>>(Wd2, Wd2t, 2048, 128);
  k_transpose_cvt<<<dim3(4, 64), 256, 0, stream>>>(mWd2, mWd2t, 2048, 128);

  k_dense1_part<<<dim3(8, 16), 256, 0, stream>>>(gq, Wg1, part1);
  k_dense1_fin<<<64, 256, 0, stream>>>(part1, bg1, hgq);
  k_dense2_part<<<32, 128, 0, stream>>>(hgq, Wg2, part2q);
  k_dense1_part<<<dim3(8, 16), 256, 0, stream>>>(gk, mWg1, part1);
  k_dense1_fin<<<64, 256, 0, stream>>>(part1, mbg1, hgk);
  k_dense2_part<<<32, 128, 0, stream>>>(hgk, mWg2, part2k);
  k_head_fin<<<8, 64, 0, stream>>>(part2q, part2k, bg2, mbg2, qg, kg, l_pos);

  k_gemm_abt<0><<<dim3(16, 49, 1), 256, 0, stream>>>(featq_bf, Wd1t, bd1, h_bf, nullptr,
                                                     6272, 2048, 1024, 1024, 1024, 2048, 0, 0.f, 0, 0);
  k_gemm_abt<4><<<dim3(1, 49, 4), 256, 0, stream>>>(h_bf, Wd2t, nullptr, e2part, nullptr,
                                                    6272, 128, 512, 2048, 2048, 128, 802816, 0.f, 512, 512);
  k_l2n_rows<<<1568, 256, 0, stream>>>(e2part, bd2, qd, qd_bf, 6272);

  k_gemm_abt<0><<<dim3(16, 49, 1), 256, 0, stream>>>(featk_bf, mWd1t, mbd1, h_bf, nullptr,
                                                     6272, 2048, 1024, 1024, 1024, 2048, 0, 0.f, 0, 0);
  k_gemm_abt<4><<<dim3(1, 49, 4), 256, 0, stream>>>(h_bf, mWd2t, nullptr, e2part, nullptr,
                                                    6272, 128, 512, 2048, 2048, 128, 802816, 0.f, 512, 512);
  k_l2n_rows<<<1568, 256, 0, stream>>>(e2part, mbd2, kd, kd_bf, 6272);

  k_gemm_abt<3><<<dim3(7, 7, 8), 256, 0, stream>>>(qd_bf, kd_bf, nullptr, pval, pidx,
                                                   784, 784, 128, 128, 128, 0, 7, 0.f,
                                                   784l * 128, 784l * 128);
  k_argmax_gather<<<6272, 64, 0, stream>>>(pval, pidx, kd_bf, matched_bf, idxf);

  k_gemm_abt<2><<<dim3(49, 49, 1), 256, 0, stream>>>(qd_bf, matched_bf, nullptr, pmax, psum,
                                                     6272, 6272, 128, 128, 128, 0, 49, TAU_INV, 0, 0);

  k_queue_nce<<<256, 256, 0, stream>>>(queue, qg, qpart_m, qpart_s);

  k_row_lse<<<1568, 256, 0, stream>>>(pmax, psum, idxf, qd, kd, diff);
  k_final<<<1, 256, 0, stream>>>(qpart_m, qpart_s, l_pos, diff, out);
}

// Round 5
// 288.954 us; speedup vs baseline: 2.7579x; 1.1794x over previous
//
#include <hip/hip_runtime.h>
#include <cstdint>

#define TAU_INV 5.0f
#define L2E 1.4426950408889634f

using ushort = unsigned short;
typedef __attribute__((ext_vector_type(8))) short s16x8;
typedef __attribute__((ext_vector_type(4))) float f32x4;

static __device__ __forceinline__ ushort f2bf(float x) {
  unsigned u = __float_as_uint(x);
  return (ushort)((u + 0x7fffu + ((u >> 16) & 1u)) >> 16);
}

static __device__ __forceinline__ float fexp2(float x) {
#if __has_builtin(__builtin_amdgcn_exp2f)
  return __builtin_amdgcn_exp2f(x);
#else
  return exp2f(x);
#endif
}
static __device__ __forceinline__ float fexpd(float a, float b) {
  return fexp2((a - b) * L2E);
}

static __device__ __forceinline__ void gload_lds16(const void* g, void* l) {
  __builtin_amdgcn_global_load_lds(
      reinterpret_cast<const __attribute__((address_space(1))) void*>(
          reinterpret_cast<uintptr_t>(g)),
      reinterpret_cast<__attribute__((address_space(3))) void*>(
          (unsigned)reinterpret_cast<uintptr_t>(l)),
      16, 0, 0);
}

// bijective XCD-chunked swizzle of the (y*gx+x) tile space (m204 formula)
static __device__ __forceinline__ void xcd_swizzle(int gx, int gy, int& bx, int& by) {
  int nwg = gx * gy;
  int flat = by * gx + bx;
  int q = nwg >> 3, r = nwg & 7;
  int xcd = flat & 7, sl = flat >> 3;
  int tile = (xcd < r ? xcd * (q + 1) : r * (q + 1) + (xcd - r) * q) + sl;
  by = tile / gx;
  bx = tile - by * gx;
}

// ---------------- fused f32->bf16 convert + partial channel pool ----------------
__global__ void k_cvt_pool(const float* __restrict__ feat, ushort* __restrict__ obf,
                           float* __restrict__ gpart) {
  int b = blockIdx.y, pc = blockIdx.x, t = threadIdx.x;
  const float* fp = feat + ((size_t)b * 784 + (size_t)pc * 7) * 1024;
  ushort* op = obf + ((size_t)b * 784 + (size_t)pc * 7) * 1024;
  float4 acc = {0.f, 0.f, 0.f, 0.f};
#pragma unroll
  for (int p = 0; p < 7; ++p) {
    float4 v = ((const float4*)(fp + (size_t)p * 1024))[t];
    acc.x += v.x; acc.y += v.y; acc.z += v.z; acc.w += v.w;
    ushort4 r;
    r.x = f2bf(v.x); r.y = f2bf(v.y); r.z = f2bf(v.z); r.w = f2bf(v.w);
    ((ushort4*)(op + (size_t)p * 1024))[t] = r;
  }
  ((float4*)(gpart + ((size_t)b * 112 + pc) * 1024))[t] = acc;
}

__global__ void k_gpool_fin(const float* __restrict__ gpart, float* __restrict__ g) {
  int idx = blockIdx.x * 256 + threadIdx.x;
  int b = idx >> 10, c = idx & 1023;
  float s = 0.f;
#pragma unroll 4
  for (int pc = 0; pc < 112; ++pc) s += gpart[((size_t)b * 112 + pc) * 1024 + c];
  g[idx] = s * (1.0f / 784.0f);
}

__global__ void k_dense1_part(const float* __restrict__ g, const float* __restrict__ W,
                              float* __restrict__ part1) {
  int d = blockIdx.x * 256 + threadIdx.x;
  int k0 = blockIdx.y * 64;
  __shared__ float gs[512];
  for (int i = threadIdx.x; i < 512; i += 256) gs[i] = g[(i >> 6) * 1024 + k0 + (i & 63)];
  __syncthreads();
  float acc[8] = {};
  for (int kk = 0; kk < 64; ++kk) {
    float w = W[(size_t)(k0 + kk) * 2048 + d];
#pragma unroll
    for (int b = 0; b < 8; ++b) acc[b] += gs[b * 64 + kk] * w;
  }
#pragma unroll
  for (int b = 0; b < 8; ++b) part1[((size_t)blockIdx.y * 8 + b) * 2048 + d] = acc[b];
}

__global__ void k_dense1_fin(const float* __restrict__ part1, const float* __restrict__ bias,
                             float* __restrict__ h) {
  int idx = blockIdx.x * 256 + threadIdx.x;
  int b = idx >> 11, d = idx & 2047;
  float s = bias[d];
#pragma unroll
  for (int ks = 0; ks < 16; ++ks) s += part1[((size_t)ks * 8 + b) * 2048 + d];
  h[idx] = fmaxf(s, 0.f);
}

__global__ void k_dense2_part(const float* __restrict__ h, const float* __restrict__ W2,
                              float* __restrict__ part2) {
  int d = threadIdx.x;
  int k0 = blockIdx.x * 64;
  __shared__ float hs[512];
  for (int i = threadIdx.x; i < 512; i += 128) hs[i] = h[(i >> 6) * 2048 + k0 + (i & 63)];
  __syncthreads();
  float acc[8] = {};
  for (int kk = 0; kk < 64; ++kk) {
    float w = W2[(size_t)(k0 + kk) * 128 + d];
#pragma unroll
    for (int b = 0; b < 8; ++b) acc[b] += hs[b * 64 + kk] * w;
  }
#pragma unroll
  for (int b = 0; b < 8; ++b) part2[((size_t)blockIdx.x * 8 + b) * 128 + d] = acc[b];
}

__global__ void k_head_fin(const float* __restrict__ p2q, const float* __restrict__ p2k,
                           const float* __restrict__ bq, const float* __restrict__ bk,
                           float* __restrict__ qg, float* __restrict__ kg,
                           float* __restrict__ lpos) {
  int b = blockIdx.x, lane = threadIdx.x;
  float q0 = bq[lane], q1 = bq[lane + 64];
  float k0 = bk[lane], k1 = bk[lane + 64];
#pragma unroll
  for (int s = 0; s < 32; ++s) {
    size_t base = ((size_t)s * 8 + b) * 128;
    q0 += p2q[base + lane]; q1 += p2q[base + lane + 64];
    k0 += p2k[base + lane]; k1 += p2k[base + lane + 64];
  }
  float sq = q0 * q0 + q1 * q1, sk = k0 * k0 + k1 * k1;
#pragma unroll
  for (int d = 1; d < 64; d <<= 1) { sq += __shfl_xor(sq, d); sk += __shfl_xor(sk, d); }
  float rq = 1.0f / sqrtf(fmaxf(sq, 1e-12f));
  float rk = 1.0f / sqrtf(fmaxf(sk, 1e-12f));
  q0 *= rq; q1 *= rq; k0 *= rk; k1 *= rk;
  qg[b * 128 + lane] = q0; qg[b * 128 + 64 + lane] = q1;
  kg[b * 128 + lane] = k0; kg[b * 128 + 64 + lane] = k1;
  float lp = q0 * k0 + q1 * k1;
#pragma unroll
  for (int d = 1; d < 64; d <<= 1) lp += __shfl_xor(lp, d);
  if (lane == 0) lpos[b] = lp;
}

// ---------------- transpose + convert ----------------
__global__ void k_transpose_cvt(const float* __restrict__ W, ushort* __restrict__ Wt, int K, int N) {
  __shared__ float tile[32][33];
  int n0 = blockIdx.x * 32, k0 = blockIdx.y * 32;
  int tx = threadIdx.x & 31, ty = threadIdx.x >> 5;
#pragma unroll
  for (int i = 0; i < 32; i += 8)
    tile[ty + i][tx] = W[(size_t)(k0 + ty + i) * N + n0 + tx];
  __syncthreads();
#pragma unroll
  for (int i = 0; i < 32; i += 8)
    Wt[(size_t)(n0 + ty + i) * K + k0 + tx] = f2bf(tile[tx][ty + i]);
}

// ---------------- MFMA GEMM: 128x128 tile, BK=64, double-buffered 2-phase ----------------
template <int EPI>
__global__ __launch_bounds__(256) void k_gemm_abt(
    const ushort* __restrict__ A, const ushort* __restrict__ B,
    const float* __restrict__ bias, void* __restrict__ o0, void* __restrict__ o1,
    int Mvalid, int Nvalid, int Kloop, int lda, int ldb, int ldOut, int ntiles,
    float scale, long sA, long sB) {
  __shared__ unsigned char smem[65536];   // 2 x (A 16K + B 16K)
  const int tid = threadIdx.x;
  int bx = blockIdx.x, by = blockIdx.y;
  const int bz = blockIdx.z;
  xcd_swizzle(gridDim.x, gridDim.y, bx, by);
  const ushort* Ab = A + (size_t)bz * sA;
  const ushort* Bb = B + (size_t)bz * sB;
  const int mBase = by * 128, nBase = bx * 128;
  const int lane = tid & 63;
  const int wid = tid >> 6;
  const int wid_u = __builtin_amdgcn_readfirstlane(wid);
  const int wm = wid >> 1, wn = wid & 1;
  const int lg = lane >> 4, li = lane & 15;
  const int lrow = lane >> 3, lchunk = lane & 7;

  const ushort* aSrc[4];
  const ushort* bSrc[4];
  int ldsOff[4];
#pragma unroll
  for (int j = 0; j < 4; ++j) {
    int r = wid_u * 32 + j * 8 + lrow;
    int gc = (lchunk ^ lrow) << 3;
    int ga = mBase + r; ga = ga < Mvalid ? ga : Mvalid - 1;
    int gb = nBase + r; gb = gb < Nvalid ? gb : Nvalid - 1;
    aSrc[j] = Ab + (size_t)ga * lda + gc;
    bSrc[j] = Bb + (size_t)gb * ldb + gc;
    ldsOff[j] = (wid_u * 32 + j * 8) * 128;
  }
  f32x4 acc[4][4] = {};

  auto STAGE = [&](int buf, int k0) {
    unsigned base = (unsigned)buf * 32768u;
#pragma unroll
    for (int j = 0; j < 4; ++j) {
      gload_lds16(aSrc[j] + k0, smem + base + ldsOff[j]);
      gload_lds16(bSrc[j] + k0, smem + base + 16384 + ldsOff[j]);
    }
  };

  const int nt = Kloop >> 6;
  STAGE(0, 0);
  __syncthreads();
  for (int t = 0; t < nt; ++t) {
    if (t + 1 < nt) STAGE((t + 1) & 1, (t + 1) << 6);
    const unsigned char* As = smem + (t & 1) * 32768;
    const unsigned char* Bs = As + 16384;
#pragma unroll
    for (int ks = 0; ks < 2; ++ks) {
      s16x8 af[4], bfr[4];
#pragma unroll
      for (int mi = 0; mi < 4; ++mi) {
        int r = wm * 64 + mi * 16 + li;
        af[mi] = *(const s16x8*)(const void*)(As + r * 128 + ((ks * 64 + lg * 16) ^ ((r & 7) << 4)));
      }
#pragma unroll
      for (int ni = 0; ni < 4; ++ni) {
        int c = wn * 64 + ni * 16 + li;
        bfr[ni] = *(const s16x8*)(const void*)(Bs + c * 128 + ((ks * 64 + lg * 16) ^ ((c & 7) << 4)));
      }
#pragma unroll
      for (int mi = 0; mi < 4; ++mi)
#pragma unroll
        for (int ni = 0; ni < 4; ++ni)
          acc[mi][ni] = __builtin_amdgcn_mfma_f32_16x16x32_bf16(af[mi], bfr[ni], acc[mi][ni], 0, 0, 0);
    }
    __syncthreads();
  }

  if constexpr (EPI == 0 || EPI == 4) {
    bool full = (mBase + 128 <= Mvalid) && (nBase + 128 <= Nvalid);
    if (full) {
#pragma unroll
      for (int ni = 0; ni < 4; ++ni) {
        int c = nBase + wn * 64 + ni * 16 + li;
        float bv = (EPI == 0) ? bias[c] : 0.f;
#pragma unroll
        for (int mi = 0; mi < 4; ++mi) {
#pragma unroll
          for (int rg = 0; rg < 4; ++rg) {
            int r = mBase + wm * 64 + mi * 16 + lg * 4 + rg;
            if constexpr (EPI == 0) {
              float v = fmaxf(acc[mi][ni][rg] + bv, 0.f);
              ((ushort*)o0)[(size_t)r * ldOut + c] = f2bf(v);
            } else {
              ((float*)o0)[(size_t)bz * ntiles + (size_t)r * ldOut + c] = acc[mi][ni][rg];
            }
          }
        }
      }
    } else {
#pragma unroll
      for (int mi = 0; mi < 4; ++mi)
#pragma unroll
        for (int ni = 0; ni < 4; ++ni) {
          int c = nBase + wn * 64 + ni * 16 + li;
#pragma unroll
          for (int rg = 0; rg < 4; ++rg) {
            int r = mBase + wm * 64 + mi * 16 + lg * 4 + rg;
            if (r < Mvalid && c < Nvalid) {
              if constexpr (EPI == 0) {
                float v = fmaxf(acc[mi][ni][rg] + bias[c], 0.f);
                ((ushort*)o0)[(size_t)r * ldOut + c] = f2bf(v);
              } else {
                ((float*)o0)[(size_t)bz * ntiles + (size_t)r * ldOut + c] = acc[mi][ni][rg];
              }
            }
          }
        }
    }
  } else if constexpr (EPI == 2) {
    __syncthreads();
    float* redm = (float*)(void*)smem;   // [128][2]
    float* reds = redm + 256;
#pragma unroll
    for (int mi = 0; mi < 4; ++mi)
#pragma unroll
      for (int rg = 0; rg < 4; ++rg) {
        float v0 = acc[mi][0][rg] * scale;
        float v1 = acc[mi][1][rg] * scale;
        float v2 = acc[mi][2][rg] * scale;
        float v3 = acc[mi][3][rg] * scale;
        float m = fmaxf(fmaxf(v0, v1), fmaxf(v2, v3));
#pragma unroll
        for (int d = 1; d < 16; d <<= 1) m = fmaxf(m, __shfl_xor(m, d));
        float s = fexpd(v0, m) + fexpd(v1, m) + fexpd(v2, m) + fexpd(v3, m);
#pragma unroll
        for (int d = 1; d < 16; d <<= 1) s += __shfl_xor(s, d);
        int rl = wm * 64 + mi * 16 + lg * 4 + rg;
        if (li == 0) { redm[rl * 2 + wn] = m; reds[rl * 2 + wn] = s; }
      }
    __syncthreads();
    if (tid < 128) {
      float m0 = redm[tid * 2], m1 = redm[tid * 2 + 1];
      float s0 = reds[tid * 2], s1 = reds[tid * 2 + 1];
      float m = fmaxf(m0, m1);
      float s = s0 * fexpd(m0, m) + s1 * fexpd(m1, m);
      size_t idx = (size_t)(mBase + tid) * ntiles + bx;
      ((float*)o0)[idx] = m;
      ((float*)o1)[idx] = s;
    }
  } else if constexpr (EPI == 3) {
    __syncthreads();
    float* redv = (float*)(void*)smem;
    int* redi = (int*)(void*)(smem + 1024);
#pragma unroll
    for (int mi = 0; mi < 4; ++mi)
#pragma unroll
      for (int rg = 0; rg < 4; ++rg) {
        float bv = -3.4e38f;
        int bi = 0x7fffffff;
#pragma unroll
        for (int ni = 0; ni < 4; ++ni) {
          int c = nBase + wn * 64 + ni * 16 + li;
          float v = (c < Nvalid) ? acc[mi][ni][rg] : -3.4e38f;
          if (v > bv || (v == bv && c < bi)) { bv = v; bi = c; }
        }
#pragma unroll
        for (int d = 1; d < 16; d <<= 1) {
          float ov = __shfl_xor(bv, d);
          int oi = __shfl_xor(bi, d);
          if (ov > bv || (ov == bv && oi < bi)) { bv = ov; bi = oi; }
        }
        int rl = wm * 64 + mi * 16 + lg * 4 + rg;
        if (li == 0) { redv[rl * 2 + wn] = bv; redi[rl * 2 + wn] = bi; }
      }
    __syncthreads();
    if (tid < 128) {
      int r = mBase + tid;
      if (r < Mvalid) {
        float v0 = redv[tid * 2], v1 = redv[tid * 2 + 1];
        int i0 = redi[tid * 2], i1 = redi[tid * 2 + 1];
        float v = v0; int bi2 = i0;
        if (v1 > v || (v1 == v && i1 < bi2)) { v = v1; bi2 = i1; }
        size_t idx = (size_t)(bz * Mvalid + r) * ntiles + bx;
        ((float*)o0)[idx] = v;
        ((int*)o1)[idx] = bi2;
      }
    }
  }
}

// ---------------- sum 4 K-slice partials + bias, l2-normalize ----------------
__global__ void k_l2n_rows(const float* __restrict__ part, const float* __restrict__ bias,
                           float* __restrict__ of, ushort* __restrict__ ob, int rows) {
  int row = blockIdx.x * 4 + (threadIdx.x >> 6);
  int lane = threadIdx.x & 63;
  if (row >= rows) return;
  size_t i0 = (size_t)row * 128 + lane;
  const size_t SL = 802816;
  float v0 = bias[lane]      + part[i0]      + part[SL + i0]      + part[2 * SL + i0]      + part[3 * SL + i0];
  float v1 = bias[lane + 64] + part[i0 + 64] + part[SL + i0 + 64] + part[2 * SL + i0 + 64] + part[3 * SL + i0 + 64];
  float ss = v0 * v0 + v1 * v1;
#pragma unroll
  for (int d = 1; d < 64; d <<= 1) ss += __shfl_xor(ss, d);
  float r = 1.0f / sqrtf(fmaxf(ss, 1e-12f));
  of[i0] = v0 * r;
  of[i0 + 64] = v1 * r;
  ob[i0] = f2bf(v0 * r);
  ob[i0 + 64] = f2bf(v1 * r);
}

// ---------------- argmax finalize + gather ----------------
__global__ void k_argmax_gather(const float* __restrict__ pval, const int* __restrict__ pidx,
                                const ushort* __restrict__ kd_bf, ushort* __restrict__ matched_bf,
                                int* __restrict__ idxf) {
  int n = blockIdx.x;
  int b = n / 784;
  float bv = pval[(size_t)n * 7];
  int bi = pidx[(size_t)n * 7];
#pragma unroll
  for (int t = 1; t < 7; ++t) {
    float v = pval[(size_t)n * 7 + t];
    int i2 = pidx[(size_t)n * 7 + t];
    if (v > bv) { bv = v; bi = i2; }
  }
  int lane = threadIdx.x;
  if (lane == 0) idxf[n] = bi;
  const ushort* src = kd_bf + (size_t)(b * 784 + bi) * 128;
  ushort* dst = matched_bf + (size_t)n * 128;
  dst[lane] = src[lane];
  dst[lane + 64] = src[lane + 64];
}

// ---------------- queue InfoNCE partials (max-first) ----------------
__global__ __launch_bounds__(256) void k_queue_nce(const float* __restrict__ queue,
                                                   const float* __restrict__ qg,
                                                   float* __restrict__ pm, float* __restrict__ ps) {
  __shared__ float qs[1024];
  int tid = threadIdx.x;
  for (int i = tid; i < 1024; i += 256) qs[i] = qg[i];
  __syncthreads();
  int r = blockIdx.x * 256 + tid;
  const float* qr = queue + (size_t)r * 128;
  float a[8] = {0, 0, 0, 0, 0, 0, 0, 0};
  for (int j = 0; j < 128; j += 4) {
    float4 v = *(const float4*)(const void*)(qr + j);
#pragma unroll
    for (int b = 0; b < 8; ++b)
      a[b] += v.x * qs[b * 128 + j] + v.y * qs[b * 128 + j + 1] +
              v.z * qs[b * 128 + j + 2] + v.w * qs[b * 128 + j + 3];
  }
  __shared__ float lm[8][4], lssum[8][4];
  int lane = tid & 63, w = tid >> 6;
#pragma unroll
  for (int b = 0; b < 8; ++b) {
    float v = a[b] * TAU_INV;
    float m = v;
#pragma unroll
    for (int d = 1; d < 64; d <<= 1) m = fmaxf(m, __shfl_xor(m, d));
    float s = fexpd(v, m);
#pragma unroll
    for (int d = 1; d < 64; d <<= 1) s += __shfl_xor(s, d);
    if (lane == 0) { lm[b][w] = m; lssum[b][w] = s; }
  }
  __syncthreads();
  if (tid < 8) {
    int b = tid;
    float m = lm[b][0], s = lssum[b][0];
#pragma unroll
    for (int i = 1; i < 4; ++i) {
      float nm = fmaxf(m, lm[b][i]);
      s = s * fexpd(m, nm) + lssum[b][i] * fexpd(lm[b][i], nm);
      m = nm;
    }
    pm[blockIdx.x * 8 + b] = m;
    ps[blockIdx.x * 8 + b] = s;
  }
}

// ---------------- per-row LSE combine (max-first) + pos dot ----------------
__global__ void k_row_lse(const float* __restrict__ pmax, const float* __restrict__ psum,
                          const int* __restrict__ idxf, const float* __restrict__ qd,
                          const float* __restrict__ kd, float* __restrict__ diff) {
  int n = blockIdx.x * 4 + (threadIdx.x >> 6);
  int lane = threadIdx.x & 63;
  float m = -3.4e38f, s = 0.f;
  if (lane < 49) {
    m = pmax[(size_t)n * 49 + lane];
    s = psum[(size_t)n * 49 + lane];
  }
  float M = m;
#pragma unroll
  for (int d = 1; d < 64; d <<= 1) M = fmaxf(M, __shfl_xor(M, d));
  s *= fexpd(m, M);
#pragma unroll
  for (int d = 1; d < 64; d <<= 1) s += __shfl_xor(s, d);
  int b = n / 784;
  int mr = b * 784 + idxf[n];
  float pos = qd[(size_t)n * 128 + lane] * kd[(size_t)mr * 128 + lane] +
              qd[(size_t)n * 128 + 64 + lane] * kd[(size_t)mr * 128 + 64 + lane];
#pragma unroll
  for (int d = 1; d < 64; d <<= 1) pos += __shfl_xor(pos, d);
  if (lane == 0) diff[n] = (M + logf(s)) - pos * TAU_INV;
}

// ---------------- final combine ----------------
__global__ void k_final(const float* __restrict__ pm, const float* __restrict__ ps,
                        const float* __restrict__ lpos, const float* __restrict__ diff,
                        float* __restrict__ out) {
  int tid = threadIdx.x;
  int lane = tid & 63, w = tid >> 6;
  __shared__ float sm[4], ssh[4];
  float lg = 0.f;
  for (int b = 0; b < 8; ++b) {
    float m = pm[tid * 8 + b], s = ps[tid * 8 + b];
    float M = m;
#pragma unroll
    for (int d = 1; d < 64; d <<= 1) M = fmaxf(M, __shfl_xor(M, d));
    s *= fexpd(m, M);
#pragma unroll
    for (int d = 1; d < 64; d <<= 1) s += __shfl_xor(s, d);
    if (lane == 0) { sm[w] = M; ssh[w] = s; }
    __syncthreads();
    if (tid == 0) {
      float M2 = sm[0], S = ssh[0];
      for (int i = 1; i < 4; ++i) {
        float nm = fmaxf(M2, sm[i]);
        S = S * fexpd(M2, nm) + ssh[i] * fexpd(sm[i], nm);
        M2 = nm;
      }
      float lp = lpos[b] * TAU_INV;
      float nm = fmaxf(M2, lp);
      S = S * fexpd(M2, nm) + fexpd(lp, nm);
      M2 = nm;
      lg += (M2 + logf(S)) - lp;
    }
    __syncthreads();
  }
  float v = 0.f;
  for (int i = tid; i < 6272; i += 256) v += diff[i];
#pragma unroll
  for (int d = 1; d < 64; d <<= 1) v += __shfl_xor(v, d);
  if (lane == 0) sm[w] = v;
  __syncthreads();
  if (tid == 0) {
    float ld = sm[0] + sm[1] + sm[2] + sm[3];
    out[0] = 0.5f * (lg * 0.125f) + 0.5f * (ld * (1.0f / 6272.0f));
  }
}

extern "C" void kernel_launch(void* const* d_in, const int* in_sizes, int n_in,
                              void* d_out, int out_size, void* d_ws, size_t ws_size,
                              hipStream_t stream) {
  (void)in_sizes; (void)n_in; (void)out_size; (void)ws_size;
  const float* feat_q = (const float*)d_in[0];
  const float* feat_k = (const float*)d_in[1];
  const float* Wg1 = (const float*)d_in[2];
  const float* bg1 = (const float*)d_in[3];
  const float* Wg2 = (const float*)d_in[4];
  const float* bg2 = (const float*)d_in[5];
  const float* Wd1 = (const float*)d_in[6];
  const float* bd1 = (const float*)d_in[7];
  const float* Wd2 = (const float*)d_in[8];
  const float* bd2 = (const float*)d_in[9];
  const float* mWg1 = (const float*)d_in[10];
  const float* mbg1 = (const float*)d_in[11];
  const float* mWg2 = (const float*)d_in[12];
  const float* mbg2 = (const float*)d_in[13];
  const float* mWd1 = (const float*)d_in[14];
  const float* mbd1 = (const float*)d_in[15];
  const float* mWd2 = (const float*)d_in[16];
  const float* mbd2 = (const float*)d_in[17];
  const float* queue = (const float*)d_in[18];
  float* out = (float*)d_out;

  char* ws = (char*)d_ws;
  size_t off = 0;
  auto alloc = [&](size_t bytes) -> void* {
    void* p = (void*)(ws + off);
    off += (bytes + 255) & ~(size_t)255;
    return p;
  };

  ushort* featq_bf = (ushort*)alloc(6272ull * 1024 * 2);
  ushort* featk_bf = (ushort*)alloc(6272ull * 1024 * 2);
  ushort* Wd1t = (ushort*)alloc(2048ull * 1024 * 2);
  ushort* mWd1t = (ushort*)alloc(2048ull * 1024 * 2);
  ushort* Wd2t = (ushort*)alloc(128ull * 2048 * 2);
  ushort* mWd2t = (ushort*)alloc(128ull * 2048 * 2);
  ushort* h_bf = (ushort*)alloc(6272ull * 2048 * 2);
  float* e2part = (float*)alloc(4ull * 6272 * 128 * 4);
  float* qd = (float*)alloc(6272ull * 128 * 4);
  float* kd = (float*)alloc(6272ull * 128 * 4);
  ushort* qd_bf = (ushort*)alloc(6272ull * 128 * 2);
  ushort* kd_bf = (ushort*)alloc(6272ull * 128 * 2);
  ushort* matched_bf = (ushort*)alloc(6272ull * 128 * 2);
  float* pmax = (float*)alloc(6272ull * 49 * 4);
  float* psum = (float*)alloc(6272ull * 49 * 4);
  float* pval = (float*)alloc(6272ull * 7 * 4);
  int* pidx = (int*)alloc(6272ull * 7 * 4);
  int* idxf = (int*)alloc(6272ull * 4);
  float* gpart = (float*)alloc(8ull * 112 * 1024 * 4);
  float* gq = (float*)alloc(8ull * 1024 * 4);
  float* gk = (float*)alloc(8ull * 1024 * 4);
  float* part1 = (float*)alloc(16ull * 8 * 2048 * 4);
  float* hgq = (float*)alloc(8ull * 2048 * 4);
  float* hgk = (float*)alloc(8ull * 2048 * 4);
  float* part2q = (float*)alloc(32ull * 8 * 128 * 4);
  float* part2k = (float*)alloc(32ull * 8 * 128 * 4);
  float* qg = (float*)alloc(8ull * 128 * 4);
  float* kg = (float*)alloc(8ull * 128 * 4);
  float* l_pos = (float*)alloc(8ull * 4);
  float* qpart_m = (float*)alloc(256ull * 8 * 4);
  float* qpart_s = (float*)alloc(256ull * 8 * 4);
  float* diff = (float*)alloc(6272ull * 4);

  k_cvt_pool<<<dim3(112, 8), 256, 0, stream>>>(feat_q, featq_bf, gpart);
  k_gpool_fin<<<32, 256, 0, stream>>>(gpart, gq);
  k_cvt_pool<<<dim3(112, 8), 256, 0, stream>>>(feat_k, featk_bf, gpart);
  k_gpool_fin<<<32, 256, 0, stream>>>(gpart, gk);

  k_transpose_cvt<<<dim3(64, 32), 256, 0, stream>>>(Wd1, Wd1t, 1024, 2048);
  k_transpose_cvt<<<dim3(64, 32), 256, 0, stream>>>(mWd1, mWd1t, 1024, 2048);
  k_transpose_cvt<<<dim3(4, 64), 256, 0, stream>>>(Wd2, Wd2t, 2048, 128);
  k_transpose_cvt<<<dim3(4, 64), 256, 0, stream>>>(mWd2, mWd2t, 2048, 128);

  k_dense1_part<<<dim3(8, 16), 256, 0, stream>>>(gq, Wg1, part1);
  k_dense1_fin<<<64, 256, 0, stream>>>(part1, bg1, hgq);
  k_dense2_part<<<32, 128, 0, stream>>>(hgq, Wg2, part2q);
  k_dense1_part<<<dim3(8, 16), 256, 0, stream>>>(gk, mWg1, part1);
  k_dense1_fin<<<64, 256, 0, stream>>>(part1, mbg1, hgk);
  k_dense2_part<<<32, 128, 0, stream>>>(hgk, mWg2, part2k);
  k_head_fin<<<8, 64, 0, stream>>>(part2q, part2k, bg2, mbg2, qg, kg, l_pos);

  k_gemm_abt<0><<<dim3(16, 49, 1), 256, 0, stream>>>(featq_bf, Wd1t, bd1, h_bf, nullptr,
                                                     6272, 2048, 1024, 1024, 1024, 2048, 0, 0.f, 0, 0);
  k_gemm_abt<4><<<dim3(1, 49, 4), 256, 0, stream>>>(h_bf, Wd2t, nullptr, e2part, nullptr,
                                                    6272, 128, 512, 2048, 2048, 128, 802816, 0.f, 512, 512);
  k_l2n_rows<<<1568, 256, 0, stream>>>(e2part, bd2, qd, qd_bf, 6272);

  k_gemm_abt<0><<<dim3(16, 49, 1), 256, 0, stream>>>(featk_bf, mWd1t, mbd1, h_bf, nullptr,
                                                     6272, 2048, 1024, 1024, 1024, 2048, 0, 0.f, 0, 0);
  k_gemm_abt<4><<<dim3(1, 49, 4), 256, 0, stream>>>(h_bf, mWd2t, nullptr, e2part, nullptr,
                                                    6272, 128, 512, 2048, 2048, 128, 802816, 0.f, 512, 512);
  k_l2n_rows<<<1568, 256, 0, stream>>>(e2part, mbd2, kd, kd_bf, 6272);

  k_gemm_abt<3><<<dim3(7, 7, 8), 256, 0, stream>>>(qd_bf, kd_bf, nullptr, pval, pidx,
                                                   784, 784, 128, 128, 128, 0, 7, 0.f,
                                                   784l * 128, 784l * 128);
  k_argmax_gather<<<6272, 64, 0, stream>>>(pval, pidx, kd_bf, matched_bf, idxf);

  k_gemm_abt<2><<<dim3(49, 49, 1), 256, 0, stream>>>(qd_bf, matched_bf, nullptr, pmax, psum,
                                                     6272, 6272, 128, 128, 128, 0, 49, TAU_INV, 0, 0);

  k_queue_nce<<<256, 256, 0, stream>>>(queue, qg, qpart_m, qpart_s);

  k_row_lse<<<1568, 256, 0, stream>>>(pmax, psum, idxf, qd, kd, diff);
  k_final<<<1, 256, 0, stream>>>(qpart_m, qpart_s, l_pos, diff, out);
}

// Round 6
// 270.425 us; speedup vs baseline: 2.9469x; 1.0685x over previous
//
#include <hip/hip_runtime.h>
#include <cstdint>

#define TAU_INV 5.0f
#define L2E 1.4426950408889634f

using ushort = unsigned short;
typedef __attribute__((ext_vector_type(8))) short s16x8;
typedef __attribute__((ext_vector_type(4))) float f32x4;

static __device__ __forceinline__ ushort f2bf(float x) {
  unsigned u = __float_as_uint(x);
  return (ushort)((u + 0x7fffu + ((u >> 16) & 1u)) >> 16);
}

static __device__ __forceinline__ float fexp2(float x) {
#if __has_builtin(__builtin_amdgcn_exp2f)
  return __builtin_amdgcn_exp2f(x);
#else
  return exp2f(x);
#endif
}

static __device__ __forceinline__ void gload_lds16(const void* g, void* l) {
  __builtin_amdgcn_global_load_lds(
      reinterpret_cast<const __attribute__((address_space(1))) void*>(
          reinterpret_cast<uintptr_t>(g)),
      reinterpret_cast<__attribute__((address_space(3))) void*>(
          (unsigned)reinterpret_cast<uintptr_t>(l)),
      16, 0, 0);
}

// bijective XCD-chunked swizzle of the (y*gx+x) tile space (m204 formula)
static __device__ __forceinline__ void xcd_swizzle(int gx, int gy, int& bx, int& by) {
  int nwg = gx * gy;
  int flat = by * gx + bx;
  int q = nwg >> 3, r = nwg & 7;
  int xcd = flat & 7, sl = flat >> 3;
  int tile = (xcd < r ? xcd * (q + 1) : r * (q + 1) + (xcd - r) * q) + sl;
  by = tile / gx;
  bx = tile - by * gx;
}

// ---------------- fused f32->bf16 convert + partial channel pool ----------------
__global__ void k_cvt_pool(const float* __restrict__ feat, ushort* __restrict__ obf,
                           float* __restrict__ gpart) {
  int b = blockIdx.y, pc = blockIdx.x, t = threadIdx.x;
  const float* fp = feat + ((size_t)b * 784 + (size_t)pc * 7) * 1024;
  ushort* op = obf + ((size_t)b * 784 + (size_t)pc * 7) * 1024;
  float4 acc = {0.f, 0.f, 0.f, 0.f};
#pragma unroll
  for (int p = 0; p < 7; ++p) {
    float4 v = ((const float4*)(fp + (size_t)p * 1024))[t];
    acc.x += v.x; acc.y += v.y; acc.z += v.z; acc.w += v.w;
    ushort4 r;
    r.x = f2bf(v.x); r.y = f2bf(v.y); r.z = f2bf(v.z); r.w = f2bf(v.w);
    ((ushort4*)(op + (size_t)p * 1024))[t] = r;
  }
  ((float4*)(gpart + ((size_t)b * 112 + pc) * 1024))[t] = acc;
}

__global__ void k_gpool_fin(const float* __restrict__ gpart, float* __restrict__ g) {
  int idx = blockIdx.x * 256 + threadIdx.x;
  int b = idx >> 10, c = idx & 1023;
  float s = 0.f;
#pragma unroll 4
  for (int pc = 0; pc < 112; ++pc) s += gpart[((size_t)b * 112 + pc) * 1024 + c];
  g[idx] = s * (1.0f / 784.0f);
}

__global__ void k_dense1_part(const float* __restrict__ g, const float* __restrict__ W,
                              float* __restrict__ part1) {
  int d = blockIdx.x * 256 + threadIdx.x;
  int k0 = blockIdx.y * 64;
  __shared__ float gs[512];
  for (int i = threadIdx.x; i < 512; i += 256) gs[i] = g[(i >> 6) * 1024 + k0 + (i & 63)];
  __syncthreads();
  float acc[8] = {};
  for (int kk = 0; kk < 64; ++kk) {
    float w = W[(size_t)(k0 + kk) * 2048 + d];
#pragma unroll
    for (int b = 0; b < 8; ++b) acc[b] += gs[b * 64 + kk] * w;
  }
#pragma unroll
  for (int b = 0; b < 8; ++b) part1[((size_t)blockIdx.y * 8 + b) * 2048 + d] = acc[b];
}

__global__ void k_dense1_fin(const float* __restrict__ part1, const float* __restrict__ bias,
                             float* __restrict__ h) {
  int idx = blockIdx.x * 256 + threadIdx.x;
  int b = idx >> 11, d = idx & 2047;
  float s = bias[d];
#pragma unroll
  for (int ks = 0; ks < 16; ++ks) s += part1[((size_t)ks * 8 + b) * 2048 + d];
  h[idx] = fmaxf(s, 0.f);
}

__global__ void k_dense2_part(const float* __restrict__ h, const float* __restrict__ W2,
                              float* __restrict__ part2) {
  int d = threadIdx.x;
  int k0 = blockIdx.x * 64;
  __shared__ float hs[512];
  for (int i = threadIdx.x; i < 512; i += 128) hs[i] = h[(i >> 6) * 2048 + k0 + (i & 63)];
  __syncthreads();
  float acc[8] = {};
  for (int kk = 0; kk < 64; ++kk) {
    float w = W2[(size_t)(k0 + kk) * 128 + d];
#pragma unroll
    for (int b = 0; b < 8; ++b) acc[b] += hs[b * 64 + kk] * w;
  }
#pragma unroll
  for (int b = 0; b < 8; ++b) part2[((size_t)blockIdx.x * 8 + b) * 128 + d] = acc[b];
}

__global__ void k_head_fin(const float* __restrict__ p2q, const float* __restrict__ p2k,
                           const float* __restrict__ bq, const float* __restrict__ bk,
                           float* __restrict__ qg, float* __restrict__ kg,
                           float* __restrict__ lpos) {
  int b = blockIdx.x, lane = threadIdx.x;
  float q0 = bq[lane], q1 = bq[lane + 64];
  float k0 = bk[lane], k1 = bk[lane + 64];
#pragma unroll
  for (int s = 0; s < 32; ++s) {
    size_t base = ((size_t)s * 8 + b) * 128;
    q0 += p2q[base + lane]; q1 += p2q[base + lane + 64];
    k0 += p2k[base + lane]; k1 += p2k[base + lane + 64];
  }
  float sq = q0 * q0 + q1 * q1, sk = k0 * k0 + k1 * k1;
#pragma unroll
  for (int d = 1; d < 64; d <<= 1) { sq += __shfl_xor(sq, d); sk += __shfl_xor(sk, d); }
  float rq = 1.0f / sqrtf(fmaxf(sq, 1e-12f));
  float rk = 1.0f / sqrtf(fmaxf(sk, 1e-12f));
  q0 *= rq; q1 *= rq; k0 *= rk; k1 *= rk;
  qg[b * 128 + lane] = q0; qg[b * 128 + 64 + lane] = q1;
  kg[b * 128 + lane] = k0; kg[b * 128 + 64 + lane] = k1;
  float lp = q0 * k0 + q1 * k1;
#pragma unroll
  for (int d = 1; d < 64; d <<= 1) lp += __shfl_xor(lp, d);
  if (lane == 0) lpos[b] = lp;
}

// ---------------- transpose + convert ----------------
__global__ void k_transpose_cvt(const float* __restrict__ W, ushort* __restrict__ Wt, int K, int N) {
  __shared__ float tile[32][33];
  int n0 = blockIdx.x * 32, k0 = blockIdx.y * 32;
  int tx = threadIdx.x & 31, ty = threadIdx.x >> 5;
#pragma unroll
  for (int i = 0; i < 32; i += 8)
    tile[ty + i][tx] = W[(size_t)(k0 + ty + i) * N + n0 + tx];
  __syncthreads();
#pragma unroll
  for (int i = 0; i < 32; i += 8)
    Wt[(size_t)(n0 + ty + i) * K + k0 + tx] = f2bf(tile[tx][ty + i]);
}

// ---------------- MFMA GEMM: 128x128 tile, BK=64, double-buffered 2-phase ----------------
// EPI 0: +bias, relu, bf16    EPI 2: per-row sum(exp(acc*scale)) partials (max-free)
// EPI 3: per-row (max,argmax) EPI 4: raw f32 at slice offset bz*ntiles
template <int EPI>
__global__ __launch_bounds__(256) void k_gemm_abt(
    const ushort* __restrict__ A, const ushort* __restrict__ B,
    const float* __restrict__ bias, void* __restrict__ o0, void* __restrict__ o1,
    int Mvalid, int Nvalid, int Kloop, int lda, int ldb, int ldOut, int ntiles,
    float scale, long sA, long sB) {
  __shared__ unsigned char smem[65536];   // 2 x (A 16K + B 16K)
  const int tid = threadIdx.x;
  int bx = blockIdx.x, by = blockIdx.y;
  const int bz = blockIdx.z;
  xcd_swizzle(gridDim.x, gridDim.y, bx, by);
  const ushort* Ab = A + (size_t)bz * sA;
  const ushort* Bb = B + (size_t)bz * sB;
  const int mBase = by * 128, nBase = bx * 128;
  const int lane = tid & 63;
  const int wid = tid >> 6;
  const int wid_u = __builtin_amdgcn_readfirstlane(wid);
  const int wm = wid >> 1, wn = wid & 1;
  const int lg = lane >> 4, li = lane & 15;
  const int lrow = lane >> 3, lchunk = lane & 7;

  const ushort* aSrc[4];
  const ushort* bSrc[4];
  int ldsOff[4];
#pragma unroll
  for (int j = 0; j < 4; ++j) {
    int r = wid_u * 32 + j * 8 + lrow;
    int gc = (lchunk ^ lrow) << 3;
    int ga = mBase + r; ga = ga < Mvalid ? ga : Mvalid - 1;
    int gb = nBase + r; gb = gb < Nvalid ? gb : Nvalid - 1;
    aSrc[j] = Ab + (size_t)ga * lda + gc;
    bSrc[j] = Bb + (size_t)gb * ldb + gc;
    ldsOff[j] = (wid_u * 32 + j * 8) * 128;
  }
  f32x4 acc[4][4] = {};

  auto STAGE = [&](int buf, int k0) {
    unsigned base = (unsigned)buf * 32768u;
#pragma unroll
    for (int j = 0; j < 4; ++j) {
      gload_lds16(aSrc[j] + k0, smem + base + ldsOff[j]);
      gload_lds16(bSrc[j] + k0, smem + base + 16384 + ldsOff[j]);
    }
  };

  const int nt = Kloop >> 6;
  STAGE(0, 0);
  __syncthreads();
  for (int t = 0; t < nt; ++t) {
    if (t + 1 < nt) STAGE((t + 1) & 1, (t + 1) << 6);
    const unsigned char* As = smem + (t & 1) * 32768;
    const unsigned char* Bs = As + 16384;
#pragma unroll
    for (int ks = 0; ks < 2; ++ks) {
      s16x8 af[4], bfr[4];
#pragma unroll
      for (int mi = 0; mi < 4; ++mi) {
        int r = wm * 64 + mi * 16 + li;
        af[mi] = *(const s16x8*)(const void*)(As + r * 128 + ((ks * 64 + lg * 16) ^ ((r & 7) << 4)));
      }
#pragma unroll
      for (int ni = 0; ni < 4; ++ni) {
        int c = wn * 64 + ni * 16 + li;
        bfr[ni] = *(const s16x8*)(const void*)(Bs + c * 128 + ((ks * 64 + lg * 16) ^ ((c & 7) << 4)));
      }
#pragma unroll
      for (int mi = 0; mi < 4; ++mi)
#pragma unroll
        for (int ni = 0; ni < 4; ++ni)
          acc[mi][ni] = __builtin_amdgcn_mfma_f32_16x16x32_bf16(af[mi], bfr[ni], acc[mi][ni], 0, 0, 0);
    }
    __syncthreads();
  }

  if constexpr (EPI == 0 || EPI == 4) {
    bool full = (mBase + 128 <= Mvalid) && (nBase + 128 <= Nvalid);
    if (full) {
#pragma unroll
      for (int ni = 0; ni < 4; ++ni) {
        int c = nBase + wn * 64 + ni * 16 + li;
        float bv = (EPI == 0) ? bias[c] : 0.f;
#pragma unroll
        for (int mi = 0; mi < 4; ++mi) {
#pragma unroll
          for (int rg = 0; rg < 4; ++rg) {
            int r = mBase + wm * 64 + mi * 16 + lg * 4 + rg;
            if constexpr (EPI == 0) {
              float v = fmaxf(acc[mi][ni][rg] + bv, 0.f);
              ((ushort*)o0)[(size_t)r * ldOut + c] = f2bf(v);
            } else {
              ((float*)o0)[(size_t)bz * ntiles + (size_t)r * ldOut + c] = acc[mi][ni][rg];
            }
          }
        }
      }
    } else {
#pragma unroll
      for (int mi = 0; mi < 4; ++mi)
#pragma unroll
        for (int ni = 0; ni < 4; ++ni) {
          int c = nBase + wn * 64 + ni * 16 + li;
#pragma unroll
          for (int rg = 0; rg < 4; ++rg) {
            int r = mBase + wm * 64 + mi * 16 + lg * 4 + rg;
            if (r < Mvalid && c < Nvalid) {
              if constexpr (EPI == 0) {
                float v = fmaxf(acc[mi][ni][rg] + bias[c], 0.f);
                ((ushort*)o0)[(size_t)r * ldOut + c] = f2bf(v);
              } else {
                ((float*)o0)[(size_t)bz * ntiles + (size_t)r * ldOut + c] = acc[mi][ni][rg];
              }
            }
          }
        }
    }
  } else if constexpr (EPI == 2) {
    // max-free: logits bounded by |dot|<=~1.01 * TAU_INV -> exp<=156, sums fp32-safe.
    // scale = TAU_INV * log2(e); per-tile partial = sum_j exp(logit_j)
    __syncthreads();
    float* reds = (float*)(void*)smem;   // [128][2]
#pragma unroll
    for (int mi = 0; mi < 4; ++mi)
#pragma unroll
      for (int rg = 0; rg < 4; ++rg) {
        float s = fexp2(acc[mi][0][rg] * scale) + fexp2(acc[mi][1][rg] * scale) +
                  fexp2(acc[mi][2][rg] * scale) + fexp2(acc[mi][3][rg] * scale);
#pragma unroll
        for (int d = 1; d < 16; d <<= 1) s += __shfl_xor(s, d);
        int rl = wm * 64 + mi * 16 + lg * 4 + rg;
        if (li == 0) reds[rl * 2 + wn] = s;
      }
    __syncthreads();
    if (tid < 128) {
      size_t idx = (size_t)(mBase + tid) * ntiles + bx;
      ((float*)o0)[idx] = reds[tid * 2] + reds[tid * 2 + 1];
    }
  } else if constexpr (EPI == 3) {
    __syncthreads();
    float* redv = (float*)(void*)smem;
    int* redi = (int*)(void*)(smem + 1024);
#pragma unroll
    for (int mi = 0; mi < 4; ++mi)
#pragma unroll
      for (int rg = 0; rg < 4; ++rg) {
        float bv = -3.4e38f;
        int bi = 0x7fffffff;
#pragma unroll
        for (int ni = 0; ni < 4; ++ni) {
          int c = nBase + wn * 64 + ni * 16 + li;
          float v = (c < Nvalid) ? acc[mi][ni][rg] : -3.4e38f;
          if (v > bv || (v == bv && c < bi)) { bv = v; bi = c; }
        }
#pragma unroll
        for (int d = 1; d < 16; d <<= 1) {
          float ov = __shfl_xor(bv, d);
          int oi = __shfl_xor(bi, d);
          if (ov > bv || (ov == bv && oi < bi)) { bv = ov; bi = oi; }
        }
        int rl = wm * 64 + mi * 16 + lg * 4 + rg;
        if (li == 0) { redv[rl * 2 + wn] = bv; redi[rl * 2 + wn] = bi; }
      }
    __syncthreads();
    if (tid < 128) {
      int r = mBase + tid;
      if (r < Mvalid) {
        float v0 = redv[tid * 2], v1 = redv[tid * 2 + 1];
        int i0 = redi[tid * 2], i1 = redi[tid * 2 + 1];
        float v = v0; int bi2 = i0;
        if (v1 > v || (v1 == v && i1 < bi2)) { v = v1; bi2 = i1; }
        size_t idx = (size_t)(bz * Mvalid + r) * ntiles + bx;
        ((float*)o0)[idx] = v;
        ((int*)o1)[idx] = bi2;
      }
    }
  }
}

// ---------------- sum 4 K-slice partials + bias, l2-normalize ----------------
__global__ void k_l2n_rows(const float* __restrict__ part, const float* __restrict__ bias,
                           float* __restrict__ of, ushort* __restrict__ ob, int rows) {
  int row = blockIdx.x * 4 + (threadIdx.x >> 6);
  int lane = threadIdx.x & 63;
  if (row >= rows) return;
  size_t i0 = (size_t)row * 128 + lane;
  const size_t SL = 802816;
  float v0 = bias[lane]      + part[i0]      + part[SL + i0]      + part[2 * SL + i0]      + part[3 * SL + i0];
  float v1 = bias[lane + 64] + part[i0 + 64] + part[SL + i0 + 64] + part[2 * SL + i0 + 64] + part[3 * SL + i0 + 64];
  float ss = v0 * v0 + v1 * v1;
#pragma unroll
  for (int d = 1; d < 64; d <<= 1) ss += __shfl_xor(ss, d);
  float r = 1.0f / sqrtf(fmaxf(ss, 1e-12f));
  of[i0] = v0 * r;
  of[i0 + 64] = v1 * r;
  ob[i0] = f2bf(v0 * r);
  ob[i0 + 64] = f2bf(v1 * r);
}

// ---------------- argmax finalize + gather ----------------
__global__ void k_argmax_gather(const float* __restrict__ pval, const int* __restrict__ pidx,
                                const ushort* __restrict__ kd_bf, ushort* __restrict__ matched_bf,
                                int* __restrict__ idxf) {
  int n = blockIdx.x;
  int b = n / 784;
  float bv = pval[(size_t)n * 7];
  int bi = pidx[(size_t)n * 7];
#pragma unroll
  for (int t = 1; t < 7; ++t) {
    float v = pval[(size_t)n * 7 + t];
    int i2 = pidx[(size_t)n * 7 + t];
    if (v > bv) { bv = v; bi = i2; }
  }
  int lane = threadIdx.x;
  if (lane == 0) idxf[n] = bi;
  const ushort* src = kd_bf + (size_t)(b * 784 + bi) * 128;
  ushort* dst = matched_bf + (size_t)n * 128;
  dst[lane] = src[lane];
  dst[lane + 64] = src[lane + 64];
}

// ---------------- queue InfoNCE partials (max-free) ----------------
__global__ __launch_bounds__(256) void k_queue_nce(const float* __restrict__ queue,
                                                   const float* __restrict__ qg,
                                                   float* __restrict__ ps) {
  __shared__ float qs[1024];
  int tid = threadIdx.x;
  for (int i = tid; i < 1024; i += 256) qs[i] = qg[i];
  __syncthreads();
  int r = blockIdx.x * 256 + tid;
  const float* qr = queue + (size_t)r * 128;
  float a[8] = {0, 0, 0, 0, 0, 0, 0, 0};
  for (int j = 0; j < 128; j += 4) {
    float4 v = *(const float4*)(const void*)(qr + j);
#pragma unroll
    for (int b = 0; b < 8; ++b)
      a[b] += v.x * qs[b * 128 + j] + v.y * qs[b * 128 + j + 1] +
              v.z * qs[b * 128 + j + 2] + v.w * qs[b * 128 + j + 3];
  }
  __shared__ float lssum[8][4];
  int lane = tid & 63, w = tid >> 6;
#pragma unroll
  for (int b = 0; b < 8; ++b) {
    float s = fexp2(a[b] * (TAU_INV * L2E));
#pragma unroll
    for (int d = 1; d < 64; d <<= 1) s += __shfl_xor(s, d);
    if (lane == 0) lssum[b][w] = s;
  }
  __syncthreads();
  if (tid < 8) {
    int b = tid;
    ps[blockIdx.x * 8 + b] = lssum[b][0] + lssum[b][1] + lssum[b][2] + lssum[b][3];
  }
}

// ---------------- per-row: sum 49 partials -> log + pos dot ----------------
__global__ void k_row_lse(const float* __restrict__ psum, const int* __restrict__ idxf,
                          const float* __restrict__ qd, const float* __restrict__ kd,
                          float* __restrict__ diff) {
  int n = blockIdx.x * 4 + (threadIdx.x >> 6);
  int lane = threadIdx.x & 63;
  float s = (lane < 49) ? psum[(size_t)n * 49 + lane] : 0.f;
#pragma unroll
  for (int d = 1; d < 64; d <<= 1) s += __shfl_xor(s, d);
  int b = n / 784;
  int mr = b * 784 + idxf[n];
  float pos = qd[(size_t)n * 128 + lane] * kd[(size_t)mr * 128 + lane] +
              qd[(size_t)n * 128 + 64 + lane] * kd[(size_t)mr * 128 + 64 + lane];
#pragma unroll
  for (int d = 1; d < 64; d <<= 1) pos += __shfl_xor(pos, d);
  if (lane == 0) diff[n] = logf(s) - pos * TAU_INV;
}

// ---------------- final combine (max-free) ----------------
__global__ void k_final(const float* __restrict__ ps, const float* __restrict__ lpos,
                        const float* __restrict__ diff, float* __restrict__ out) {
  int tid = threadIdx.x;
  int lane = tid & 63, w = tid >> 6;
  __shared__ float sm[4];
  float lg = 0.f;
  for (int b = 0; b < 8; ++b) {
    float s = ps[tid * 8 + b];
#pragma unroll
    for (int d = 1; d < 64; d <<= 1) s += __shfl_xor(s, d);
    if (lane == 0) sm[w] = s;
    __syncthreads();
    if (tid == 0) {
      float S = sm[0] + sm[1] + sm[2] + sm[3];
      float lp = lpos[b] * TAU_INV;
      S += fexp2(lp * L2E);
      lg += logf(S) - lp;
    }
    __syncthreads();
  }
  float v = 0.f;
  for (int i = tid; i < 6272; i += 256) v += diff[i];
#pragma unroll
  for (int d = 1; d < 64; d <<= 1) v += __shfl_xor(v, d);
  if (lane == 0) sm[w] = v;
  __syncthreads();
  if (tid == 0) {
    float ld = sm[0] + sm[1] + sm[2] + sm[3];
    out[0] = 0.5f * (lg * 0.125f) + 0.5f * (ld * (1.0f / 6272.0f));
  }
}

extern "C" void kernel_launch(void* const* d_in, const int* in_sizes, int n_in,
                              void* d_out, int out_size, void* d_ws, size_t ws_size,
                              hipStream_t stream) {
  (void)in_sizes; (void)n_in; (void)out_size; (void)ws_size;
  const float* feat_q = (const float*)d_in[0];
  const float* feat_k = (const float*)d_in[1];
  const float* Wg1 = (const float*)d_in[2];
  const float* bg1 = (const float*)d_in[3];
  const float* Wg2 = (const float*)d_in[4];
  const float* bg2 = (const float*)d_in[5];
  const float* Wd1 = (const float*)d_in[6];
  const float* bd1 = (const float*)d_in[7];
  const float* Wd2 = (const float*)d_in[8];
  const float* bd2 = (const float*)d_in[9];
  const float* mWg1 = (const float*)d_in[10];
  const float* mbg1 = (const float*)d_in[11];
  const float* mWg2 = (const float*)d_in[12];
  const float* mbg2 = (const float*)d_in[13];
  const float* mWd1 = (const float*)d_in[14];
  const float* mbd1 = (const float*)d_in[15];
  const float* mWd2 = (const float*)d_in[16];
  const float* mbd2 = (const float*)d_in[17];
  const float* queue = (const float*)d_in[18];
  float* out = (float*)d_out;

  char* ws = (char*)d_ws;
  size_t off = 0;
  auto alloc = [&](size_t bytes) -> void* {
    void* p = (void*)(ws + off);
    off += (bytes + 255) & ~(size_t)255;
    return p;
  };

  ushort* featq_bf = (ushort*)alloc(6272ull * 1024 * 2);
  ushort* featk_bf = (ushort*)alloc(6272ull * 1024 * 2);
  ushort* Wd1t = (ushort*)alloc(2048ull * 1024 * 2);
  ushort* mWd1t = (ushort*)alloc(2048ull * 1024 * 2);
  ushort* Wd2t = (ushort*)alloc(128ull * 2048 * 2);
  ushort* mWd2t = (ushort*)alloc(128ull * 2048 * 2);
  ushort* h_bf = (ushort*)alloc(6272ull * 2048 * 2);
  float* e2part = (float*)alloc(4ull * 6272 * 128 * 4);
  float* qd = (float*)alloc(6272ull * 128 * 4);
  float* kd = (float*)alloc(6272ull * 128 * 4);
  ushort* qd_bf = (ushort*)alloc(6272ull * 128 * 2);
  ushort* kd_bf = (ushort*)alloc(6272ull * 128 * 2);
  ushort* matched_bf = (ushort*)alloc(6272ull * 128 * 2);
  float* psum = (float*)alloc(6272ull * 49 * 4);
  float* pval = (float*)alloc(6272ull * 7 * 4);
  int* pidx = (int*)alloc(6272ull * 7 * 4);
  int* idxf = (int*)alloc(6272ull * 4);
  float* gpart = (float*)alloc(8ull * 112 * 1024 * 4);
  float* gq = (float*)alloc(8ull * 1024 * 4);
  float* gk = (float*)alloc(8ull * 1024 * 4);
  float* part1 = (float*)alloc(16ull * 8 * 2048 * 4);
  float* hgq = (float*)alloc(8ull * 2048 * 4);
  float* hgk = (float*)alloc(8ull * 2048 * 4);
  float* part2q = (float*)alloc(32ull * 8 * 128 * 4);
  float* part2k = (float*)alloc(32ull * 8 * 128 * 4);
  float* qg = (float*)alloc(8ull * 128 * 4);
  float* kg = (float*)alloc(8ull * 128 * 4);
  float* l_pos = (float*)alloc(8ull * 4);
  float* qpart_s = (float*)alloc(256ull * 8 * 4);
  float* diff = (float*)alloc(6272ull * 4);

  k_cvt_pool<<<dim3(112, 8), 256, 0, stream>>>(feat_q, featq_bf, gpart);
  k_gpool_fin<<<32, 256, 0, stream>>>(gpart, gq);
  k_cvt_pool<<<dim3(112, 8), 256, 0, stream>>>(feat_k, featk_bf, gpart);
  k_gpool_fin<<<32, 256, 0, stream>>>(gpart, gk);

  k_transpose_cvt<<<dim3(64, 32), 256, 0, stream>>>(Wd1, Wd1t, 1024, 2048);
  k_transpose_cvt<<<dim3(64, 32), 256, 0, stream>>>(mWd1, mWd1t, 1024, 2048);
  k_transpose_cvt<<<dim3(4, 64), 256, 0, stream>>>(Wd2, Wd2t, 2048, 128);
  k_transpose_cvt<<<dim3(4, 64), 256, 0, stream>>>(mWd2, mWd2t, 2048, 128);

  k_dense1_part<<<dim3(8, 16), 256, 0, stream>>>(gq, Wg1, part1);
  k_dense1_fin<<<64, 256, 0, stream>>>(part1, bg1, hgq);
  k_dense2_part<<<32, 128, 0, stream>>>(hgq, Wg2, part2q);
  k_dense1_part<<<dim3(8, 16), 256, 0, stream>>>(gk, mWg1, part1);
  k_dense1_fin<<<64, 256, 0, stream>>>(part1, mbg1, hgk);
  k_dense2_part<<<32, 128, 0, stream>>>(hgk, mWg2, part2k);
  k_head_fin<<<8, 64, 0, stream>>>(part2q, part2k, bg2, mbg2, qg, kg, l_pos);

  k_gemm_abt<0><<<dim3(16, 49, 1), 256, 0, stream>>>(featq_bf, Wd1t, bd1, h_bf, nullptr,
                                                     6272, 2048, 1024, 1024, 1024, 2048, 0, 0.f, 0, 0);
  k_gemm_abt<4><<<dim3(1, 49, 4), 256, 0, stream>>>(h_bf, Wd2t, nullptr, e2part, nullptr,
                                                    6272, 128, 512, 2048, 2048, 128, 802816, 0.f, 512, 512);
  k_l2n_rows<<<1568, 256, 0, stream>>>(e2part, bd2, qd, qd_bf, 6272);

  k_gemm_abt<0><<<dim3(16, 49, 1), 256, 0, stream>>>(featk_bf, mWd1t, mbd1, h_bf, nullptr,
                                                     6272, 2048, 1024, 1024, 1024, 2048, 0, 0.f, 0, 0);
  k_gemm_abt<4><<<dim3(1, 49, 4), 256, 0, stream>>>(h_bf, mWd2t, nullptr, e2part, nullptr,
                                                    6272, 128, 512, 2048, 2048, 128, 802816, 0.f, 512, 512);
  k_l2n_rows<<<1568, 256, 0, stream>>>(e2part, mbd2, kd, kd_bf, 6272);

  k_gemm_abt<3><<<dim3(7, 7, 8), 256, 0, stream>>>(qd_bf, kd_bf, nullptr, pval, pidx,
                                                   784, 784, 128, 128, 128, 0, 7, 0.f,
                                                   784l * 128, 784l * 128);
  k_argmax_gather<<<6272, 64, 0, stream>>>(pval, pidx, kd_bf, matched_bf, idxf);

  // dense InfoNCE partials: scale folds TAU_INV * log2(e) for v_exp_f32
  k_gemm_abt<2><<<dim3(49, 49, 1), 256, 0, stream>>>(qd_bf, matched_bf, nullptr, psum, nullptr,
                                                     6272, 6272, 128, 128, 128, 0, 49,
                                                     TAU_INV * L2E, 0, 0);

  k_queue_nce<<<256, 256, 0, stream>>>(queue, qg, qpart_s);

  k_row_lse<<<1568, 256, 0, stream>>>(psum, idxf, qd, kd, diff);
  k_final<<<1, 256, 0, stream>>>(qpart_s, l_pos, diff, out);
}